// Round 6
// baseline (303.932 us; speedup 1.0000x reference)
//
#include <hip/hip_runtime.h>
#include <hip/hip_bf16.h>

typedef __bf16 bf16;
typedef __attribute__((ext_vector_type(8))) __bf16 bf16x8;
typedef __attribute__((ext_vector_type(4))) __bf16 bf16x4;
typedef __attribute__((ext_vector_type(2))) __bf16 bf16x2;
typedef __attribute__((ext_vector_type(16))) float floatx16;
typedef unsigned int u32;

#define MFMA32(a, b, c) __builtin_amdgcn_mfma_f32_32x32x16_bf16((a), (b), (c), 0, 0, 0)

#define DIM 384
#define T1 3136   // 56*56
#define T2 784    // 28*28
#define T2P 832   // padded t for Vt columns
#define B_ 8
#define EPSV 1e-5f

__device__ __forceinline__ void gload_lds16(const bf16* g, bf16* l) {
  __builtin_amdgcn_global_load_lds(
      (const __attribute__((address_space(1))) void*)g,
      (__attribute__((address_space(3))) void*)l, 16, 0, 0);
}

__device__ __forceinline__ u32 pk2(float a, float b) {
  bf16x2 t = (bf16x2){(bf16)a, (bf16)b};
  return *reinterpret_cast<u32*>(&t);
}

// ---------------- fused depthwise convs + BN (q stride-1; k,v stride-2) + wcvt ------
__global__ void conv_fused_kernel(const float* __restrict__ x,
    const float* __restrict__ wqc, const float* __restrict__ gq, const float* __restrict__ bq,
    const float* __restrict__ mq, const float* __restrict__ vq,
    const float* __restrict__ wkc, const float* __restrict__ gk, const float* __restrict__ bk,
    const float* __restrict__ mk, const float* __restrict__ vk,
    const float* __restrict__ wvc, const float* __restrict__ gv, const float* __restrict__ bv,
    const float* __restrict__ mv, const float* __restrict__ vvv,
    bf16* __restrict__ qout, bf16* __restrict__ kout, bf16* __restrict__ vout,
    const float* __restrict__ w0, const float* __restrict__ w1,
    const float* __restrict__ w2, const float* __restrict__ w3,
    bf16* __restrict__ d0, bf16* __restrict__ d1,
    bf16* __restrict__ d2, bf16* __restrict__ d3) {
  int blk = blockIdx.x;
  int c = threadIdx.x;           // 0..383
  int gid = blk * DIM + c;
  if (gid < 147456) {            // folded weight conversion (first 384 blocks)
    d0[gid] = (bf16)w0[gid]; d1[gid] = (bf16)w1[gid];
    d2[gid] = (bf16)w2[gid]; d3[gid] = (bf16)w3[gid];
  }
  int xg = blk % 14;
  int y = (blk / 14) % 56;
  int b = blk / (14 * 56);
  int x0 = xg * 4;
  const float* xb = x + (size_t)b * T1 * DIM;
  float in[3][6];
#pragma unroll
  for (int r = 0; r < 3; ++r) {
    int yy = y + r - 1;
#pragma unroll
    for (int cc = 0; cc < 6; ++cc) {
      int xc = x0 + cc - 1;
      in[r][cc] = (yy >= 0 && yy < 56 && xc >= 0 && xc < 56)
                      ? xb[(yy * 56 + xc) * DIM + c] : 0.f;
    }
  }
  // q path
  {
    float wr[9];
#pragma unroll
    for (int i = 0; i < 9; ++i) wr[i] = wqc[c * 9 + i];
    float a = rsqrtf(vq[c] + EPSV) * gq[c];
    float bia = bq[c] - mq[c] * a;
#pragma unroll
    for (int p = 0; p < 4; ++p) {
      float s = 0.f;
#pragma unroll
      for (int r = 0; r < 3; ++r)
#pragma unroll
        for (int dx = 0; dx < 3; ++dx) s += in[r][p + dx] * wr[r * 3 + dx];
      qout[((size_t)b * T1 + y * 56 + x0 + p) * DIM + c] = (bf16)(s * a + bia);
    }
  }
  // kv path (block-uniform branch)
  if ((y & 1) == 0) {
    int y2 = y >> 1;
    float wk9[9], wv9[9];
#pragma unroll
    for (int i = 0; i < 9; ++i) { wk9[i] = wkc[c * 9 + i]; wv9[i] = wvc[c * 9 + i]; }
    float ak = rsqrtf(vk[c] + EPSV) * gk[c];
    float av = rsqrtf(vvv[c] + EPSV) * gv[c];
    float bik = bk[c] - mk[c] * ak;
    float biv = bv[c] - mv[c] * av;
#pragma unroll
    for (int p2 = 0; p2 < 2; ++p2) {
      float sk = 0.f, sv = 0.f;
#pragma unroll
      for (int r = 0; r < 3; ++r)
#pragma unroll
        for (int dx = 0; dx < 3; ++dx) {
          float xv = in[r][2 * p2 + dx];
          sk += xv * wk9[r * 3 + dx];
          sv += xv * wv9[r * 3 + dx];
        }
      size_t o = ((size_t)b * T2 + y2 * 28 + (x0 >> 1) + p2) * DIM + c;
      kout[o] = (bf16)(sk * ak + bik);
      vout[o] = (bf16)(sv * av + biv);
    }
  }
}

// ---------------- barrier-free per-wave GEMM: 64x64 tile per wave ------------------
// R11: every structural variant with a per-BK-step block barrier (R0/R7/R10) pinned
// MfmaUtil at 5.5-7.6% at this shape (K=384: 12-step loop never reaches steady
// state; ~1 block/CU resident -> each barrier globalizes the slowest wave's stall).
// This kernel has NO barriers: each wave owns a private 64x64 tile, private
// triple-buffered LDS (BK=16), per-wave counted vmcnt (depth-2 prefetch), and
// register-double-buffered fragments (LOADF(s+1) issued before MFMA(s)).
// Frag reads are contiguous 1KB per b128 group -> zero bank conflicts, no swizzle.
// 64-thread blocks; all task dims divide exactly -> no guards.
#define WBK 16
#define WBUF (64 * WBK)      // elems per LDS slice (2 KB)
__device__ __forceinline__
void wgemm_body(const bf16* A, const bf16* Bw, void* out, const float* bias,
                int mode, float scale, int m0, int n0, bf16* Ab, bf16* Bb) {
  int lane = threadIdx.x;                 // 64-thread block = 1 wave
  int l32 = lane & 31, hi = lane >> 5;

  // staging: one instr = 32 rows x 32 B; lane -> (row=lane>>1, half=lane&1)
  const bf16* ag = &A[(size_t)(m0 + (lane >> 1)) * DIM + (lane & 1) * 8];
  const bf16* bg = &Bw[(size_t)(n0 + (lane >> 1)) * DIM + (lane & 1) * 8];

  floatx16 acc[2][2];
  acc[0][0] = (floatx16)0.f; acc[0][1] = (floatx16)0.f;
  acc[1][0] = (floatx16)0.f; acc[1][1] = (floatx16)0.f;

  const int NS = DIM / WBK;  // 24

#define STAGE(s) {                                            \
    bf16* ad = Ab + ((s) % 3) * WBUF;                         \
    bf16* bd = Bb + ((s) % 3) * WBUF;                         \
    int kk = (s) * WBK;                                       \
    gload_lds16(ag + kk, ad);                                 \
    gload_lds16(ag + (size_t)32 * DIM + kk, ad + 32 * WBK);   \
    gload_lds16(bg + kk, bd);                                 \
    gload_lds16(bg + (size_t)32 * DIM + kk, bd + 32 * WBK);   \
  }

  bf16x8 fa[2][2], fb[2][2];
#define LOADF(s) {                                                        \
    const bf16* As = Ab + ((s) % 3) * WBUF;                               \
    const bf16* Bs = Bb + ((s) % 3) * WBUF;                               \
    fa[(s) & 1][0] = *(const bf16x8*)&As[(l32) * WBK + hi * 8];           \
    fa[(s) & 1][1] = *(const bf16x8*)&As[(32 + l32) * WBK + hi * 8];      \
    fb[(s) & 1][0] = *(const bf16x8*)&Bs[(l32) * WBK + hi * 8];           \
    fb[(s) & 1][1] = *(const bf16x8*)&Bs[(32 + l32) * WBK + hi * 8];      \
  }

  STAGE(0);
  STAGE(1);
  asm volatile("s_waitcnt vmcnt(4)" ::: "memory");   // step-0 loads landed
  LOADF(0);
#pragma unroll
  for (int s = 0; s < NS; ++s) {
    if (s + 2 < NS) {
      STAGE(s + 2);                                   // buf (s+2)%3: reads retired at s-1
      asm volatile("s_waitcnt vmcnt(4)" ::: "memory");// retire step s+1's 4 loads
      LOADF(s + 1);
    } else if (s + 1 < NS) {
      asm volatile("s_waitcnt vmcnt(0)" ::: "memory");
      LOADF(s + 1);
    }
    const int p = s & 1;
#pragma unroll
    for (int mt = 0; mt < 2; ++mt)
#pragma unroll
      for (int nt = 0; nt < 2; ++nt)
        acc[mt][nt] = MFMA32(fa[p][mt], fb[p][nt], acc[mt][nt]);
  }
#undef STAGE
#undef LOADF
  // epilogue: C layout col=lane&31, row=(r&3)+8*(r>>2)+4*hi (R9/R10-verified)
#pragma unroll
  for (int mt = 0; mt < 2; ++mt) {
#pragma unroll
    for (int nt = 0; nt < 2; ++nt) {
      int col = n0 + nt * 32 + l32;
#pragma unroll
      for (int r = 0; r < 16; ++r) {
        int row = m0 + mt * 32 + (r & 3) + 8 * (r >> 2) + 4 * hi;
        float v = acc[mt][nt][r];
        if (mode == 3) {
          ((float*)out)[(size_t)row * DIM + col] = v + bias[col];
        } else if (mode == 2) {
          int b = row / T2;
          int t = row - b * T2;
          ((bf16*)out)[((size_t)b * DIM + col) * T2P + t] = (bf16)v;
        } else if (mode == 0) {
          ((bf16*)out)[(size_t)row * DIM + col] = (bf16)v;
        } else {
          ((bf16*)out)[(size_t)row * DIM + col] = (bf16)(v * scale);
        }
      }
    }
  }
}

// Q (392*6=2352) + K (98*6=588) + V (588) wave-tasks = 3528 = 8*441.
// Bijective XCD chunking: t=(bx&7)*441+(bx>>3) -> each XCD gets a contiguous task
// range (A-panels + its weight matrix L2-resident; perf-only assumption bx%8=XCD).
__global__ __launch_bounds__(64, 3)
void qkv_gemm_kernel(const bf16* q_act, const bf16* k_act, const bf16* v_act,
                     const bf16* wqb, const bf16* wkb, const bf16* wvb,
                     bf16* Qp, bf16* Kp, bf16* Vtp, float qscale) {
  __shared__ bf16 Ab[3 * WBUF];   // 6 KB
  __shared__ bf16 Bb[3 * WBUF];   // 6 KB
  int bx = blockIdx.x;
  int t = (bx & 7) * 441 + (bx >> 3);
  const bf16 *A, *Bw; void* out; int mode, ti; float scale = 1.f;
  if (t < 2352)      { A = q_act; Bw = wqb; out = Qp;  mode = 1; ti = t;        scale = qscale; }
  else if (t < 2940) { A = k_act; Bw = wkb; out = Kp;  mode = 0; ti = t - 2352; }
  else               { A = v_act; Bw = wvb; out = Vtp; mode = 2; ti = t - 2940; }
  wgemm_body(A, Bw, out, nullptr, mode, scale, (ti / 6) * 64, (ti % 6) * 64, Ab, Bb);
}

__global__ __launch_bounds__(64, 3)
void last_gemm_kernel(const bf16* A, const bf16* Bw, float* out, const float* bias) {
  __shared__ bf16 Ab[3 * WBUF];
  __shared__ bf16 Bb[3 * WBUF];
  int bx = blockIdx.x;
  int t = (bx & 7) * 294 + (bx >> 3);     // 2352 = 8*294
  wgemm_body(A, Bw, out, bias, 3, 1.f, (t / 6) * 64, (t % 6) * 64, Ab, Bb);
}

// ---------------- flash attention, S^T/O^T form, 32x32 MFMA, in-register P --------
// R9 (proven): swapped QK^T lands P in the PV B-operand lane; exp2 in-reg ->
// bf16x2 pack -> __shfl_xor(32) -> PV. No P LDS. 16 KB LDS, launch_bounds(256,4).
__global__ __launch_bounds__(256, 4)
void attn_kernel(const bf16* __restrict__ Qp, const bf16* __restrict__ Kp,
                 const bf16* __restrict__ Vt, bf16* __restrict__ Ob) {
  __shared__ bf16 Kl[64 * 64];            // [t][d], chunk-XOR swizzled (8 KB)
  __shared__ bf16 Vl[64 * 64];            // [d][t], chunk-XOR swizzled (8 KB)
  int bx = blockIdx.x;
  int xcd = bx & 7, j = bx >> 3;
  int g = xcd + 8 * (j / 25);             // (b,h) group 0..47, fixed per XCD
  int qblk = j % 25;
  int h = g % 6;
  int b = g / 6;
  int tid = threadIdx.x, w = tid >> 6, lane = tid & 63;
  int l32 = lane & 31, hi = lane >> 5;
  int q0w = qblk * 128 + w * 32;

  // Q fragments, B-operand of 32x32x16: n=lane&31=q, k=hi*8+j -> d=kk*16+hi*8+j
  bf16x8 qf[4];
  {
    int qi = q0w + l32;
    qi = qi < T1 ? qi : T1 - 1;
    const bf16* qp = &Qp[((size_t)b * T1 + qi) * DIM + h * 64];
#pragma unroll
    for (int kk = 0; kk < 4; ++kk) qf[kk] = *(const bf16x8*)&qp[kk * 16 + hi * 8];
  }
  floatx16 oacc[2];
  oacc[0] = (floatx16)0.f;
  oacc[1] = (floatx16)0.f;
  float lsum = 0.f;

  int rsub = lane >> 3;
  int chnk = (lane & 7) ^ rsub;
  const bf16* kg0 = &Kp[((size_t)b * T2 + w * 16 + rsub) * DIM + h * 64 + chnk * 8];
  const bf16* kg1 = kg0 + (size_t)8 * DIM;
  const bf16* vg0 = &Vt[((size_t)b * DIM + h * 64 + w * 16 + rsub) * T2P + chnk * 8];
  const bf16* vg1 = vg0 + (size_t)8 * T2P;
  bf16* kl0 = &Kl[(w * 16) * 64];
  bf16* kl1 = &Kl[(w * 16 + 8) * 64];
  bf16* vl0 = &Vl[(w * 16) * 64];
  bf16* vl1 = &Vl[(w * 16 + 8) * 64];

  int key = lane & 7;                     // fragment-read swizzle key (= row&7)

  for (int it = 0; it < 12; ++it) {
    __syncthreads();                      // prev iter's tile reads done
    gload_lds16(kg0, kl0);
    gload_lds16(kg1, kl1);
    gload_lds16(vg0, vl0);
    gload_lds16(vg1, vl1);
    __syncthreads();                      // drains vmcnt: tiles ready
#pragma unroll
    for (int tt = 0; tt < 2; ++tt) {      // two 32-t tiles
      floatx16 s = (floatx16)0.f;
#pragma unroll
      for (int kk = 0; kk < 4; ++kk) {    // d = kk*16 + hi*8 + j
        bf16x8 kf = *(const bf16x8*)&Kl[(tt * 32 + l32) * 64 + ((kk * 2 + hi) ^ key) * 8];
        s = MFMA32(kf, qf[kk], s);
      }
      float e[16];
#pragma unroll
      for (int r = 0; r < 16; ++r) {
        e[r] = __builtin_amdgcn_exp2f(s[r]);
        lsum += e[r];
      }
#pragma unroll
      for (int kkl = 0; kkl < 2; ++kkl) {
        int r0 = kkl * 8;
        u32 pA = pk2(e[r0 + 0], e[r0 + 1]);
        u32 pB = pk2(e[r0 + 2], e[r0 + 3]);
        u32 pC = pk2(e[r0 + 4], e[r0 + 5]);
        u32 pD = pk2(e[r0 + 6], e[r0 + 7]);
        u32 sA = __shfl_xor(pA, 32);
        u32 sB = __shfl_xor(pB, 32);
        u32 sC = __shfl_xor(pC, 32);
        u32 sD = __shfl_xor(pD, 32);
        union { u32 u[4]; bf16x8 v; } pf;
        pf.u[0] = hi ? sC : pA;
        pf.u[1] = hi ? sD : pB;
        pf.u[2] = hi ? pC : sA;
        pf.u[3] = hi ? pD : sB;
        int kk = tt * 2 + kkl;            // t-chunk for V: t = kk*16 + hi*8 + j
#pragma unroll
        for (int dt = 0; dt < 2; ++dt) {
          bf16x8 vf = *(const bf16x8*)&Vl[(dt * 32 + l32) * 64 + ((kk * 2 + hi) ^ key) * 8];
          oacc[dt] = MFMA32(vf, pf.v, oacc[dt]);
        }
      }
    }
    kg0 += (size_t)64 * DIM; kg1 += (size_t)64 * DIM;
    vg0 += 64; vg1 += 64;
  }
  // tail: t 768..783 (16 rows land in reg group r0..7; clamped rows never consumed)
  {
    int tq = 768 + l32;
    tq = tq < T2 ? tq : T2 - 1;
    const bf16* kp2 = &Kp[((size_t)b * T2 + tq) * DIM + h * 64];
    floatx16 s = (floatx16)0.f;
#pragma unroll
    for (int kk = 0; kk < 4; ++kk) {
      bf16x8 kf = *(const bf16x8*)&kp2[kk * 16 + hi * 8];
      s = MFMA32(kf, qf[kk], s);
    }
    float e[8];
#pragma unroll
    for (int r = 0; r < 8; ++r) {
      e[r] = __builtin_amdgcn_exp2f(s[r]);
      lsum += e[r];
    }
    u32 pA = pk2(e[0], e[1]);
    u32 pB = pk2(e[2], e[3]);
    u32 pC = pk2(e[4], e[5]);
    u32 pD = pk2(e[6], e[7]);
    u32 sA = __shfl_xor(pA, 32);
    u32 sB = __shfl_xor(pB, 32);
    u32 sC = __shfl_xor(pC, 32);
    u32 sD = __shfl_xor(pD, 32);
    union { u32 u[4]; bf16x8 v; } pf;
    pf.u[0] = hi ? sC : pA;
    pf.u[1] = hi ? sD : pB;
    pf.u[2] = hi ? pC : sA;
    pf.u[3] = hi ? pD : sB;
#pragma unroll
    for (int dt = 0; dt < 2; ++dt) {
      const bf16* vp2 = &Vt[((size_t)b * DIM + h * 64 + dt * 32 + l32) * T2P + 768 + hi * 8];
      bf16x8 vf = *(const bf16x8*)vp2;
      oacc[dt] = MFMA32(vf, pf.v, oacc[dt]);
    }
  }
  // epilogue
  lsum += __shfl_xor(lsum, 32);
  float inv = 1.f / lsum;
  int qg = q0w + l32;
  if (qg < T1) {
    bf16* op = &Ob[((size_t)b * T1 + qg) * DIM + h * 64];
#pragma unroll
    for (int dt = 0; dt < 2; ++dt) {
#pragma unroll
      for (int gr = 0; gr < 4; ++gr) {
        bf16x4 ov = (bf16x4){(bf16)(oacc[dt][gr * 4 + 0] * inv),
                             (bf16)(oacc[dt][gr * 4 + 1] * inv),
                             (bf16)(oacc[dt][gr * 4 + 2] * inv),
                             (bf16)(oacc[dt][gr * 4 + 3] * inv)};
        *(bf16x4*)&op[dt * 32 + gr * 8 + hi * 4] = ov;
      }
    }
  }
}

// ---------------- launch ----------------
extern "C" void kernel_launch(void* const* d_in, const int* in_sizes, int n_in,
                              void* d_out, int out_size, void* d_ws, size_t ws_size,
                              hipStream_t stream) {
  (void)in_sizes; (void)n_in; (void)out_size; (void)ws_size;
  const float* x      = (const float*)d_in[0];
  const float* conv_q = (const float*)d_in[3];
  const float* bnq_s  = (const float*)d_in[4];
  const float* bnq_b  = (const float*)d_in[5];
  const float* bnq_m  = (const float*)d_in[6];
  const float* bnq_v  = (const float*)d_in[7];
  const float* conv_k = (const float*)d_in[8];
  const float* bnk_s  = (const float*)d_in[9];
  const float* bnk_b  = (const float*)d_in[10];
  const float* bnk_m  = (const float*)d_in[11];
  const float* bnk_v  = (const float*)d_in[12];
  const float* conv_v = (const float*)d_in[13];
  const float* bnv_s  = (const float*)d_in[14];
  const float* bnv_b  = (const float*)d_in[15];
  const float* bnv_m  = (const float*)d_in[16];
  const float* bnv_v  = (const float*)d_in[17];
  const float* wq     = (const float*)d_in[18];
  const float* wk     = (const float*)d_in[19];
  const float* wv     = (const float*)d_in[20];
  const float* wl     = (const float*)d_in[21];
  const float* b_last = (const float*)d_in[22];

  char* ws = (char*)d_ws;
  bf16* q_act = (bf16*)(ws + 0);               // 19267584; reused as attention output
  bf16* k_act = (bf16*)(ws + 19267584);        // 4816896
  bf16* v_act = (bf16*)(ws + 24084480);        // 4816896
  bf16* Qp    = (bf16*)(ws + 28901376);        // 19267584 (pre-scaled by SCALE*log2e)
  bf16* Kp    = (bf16*)(ws + 48168960);        // 4816896
  bf16* Vtp   = (bf16*)(ws + 52985856);        // 8*384*832*2 = 5111808  [B][384][T2P]
  bf16* wqb   = (bf16*)(ws + 58097664);        // 294912 each, x4
  bf16* wkb   = wqb + 147456;
  bf16* wvb   = wkb + 147456;
  bf16* wlb   = wvb + 147456;

  const float QSCALE = 0.05103103630798288f * 1.4426950408889634f;  // 384^-0.5 * log2e

  conv_fused_kernel<<<B_ * 56 * 14, DIM, 0, stream>>>(
      x,
      conv_q, bnq_s, bnq_b, bnq_m, bnq_v,
      conv_k, bnk_s, bnk_b, bnk_m, bnk_v,
      conv_v, bnv_s, bnv_b, bnv_m, bnv_v,
      q_act, k_act, v_act,
      wq, wk, wv, wl, wqb, wkb, wvb, wlb);

  qkv_gemm_kernel<<<3528, 64, 0, stream>>>(q_act, k_act, v_act, wqb, wkb, wvb,
                                           Qp, Kp, Vtp, QSCALE);

  attn_kernel<<<25 * 6 * B_, 256, 0, stream>>>(Qp, Kp, Vtp, q_act);

  last_gemm_kernel<<<2352, 64, 0, stream>>>(q_act, wlb, (float*)d_out, b_last);
}

// Round 7
// 287.254 us; speedup vs baseline: 1.0581x; 1.0581x over previous
//
#include <hip/hip_runtime.h>
#include <hip/hip_bf16.h>

typedef __bf16 bf16;
typedef __attribute__((ext_vector_type(8))) __bf16 bf16x8;
typedef __attribute__((ext_vector_type(4))) __bf16 bf16x4;
typedef __attribute__((ext_vector_type(2))) __bf16 bf16x2;
typedef __attribute__((ext_vector_type(4))) float floatx4;
typedef __attribute__((ext_vector_type(16))) float floatx16;
typedef unsigned int u32;

#define MFMA16(a, b, c) __builtin_amdgcn_mfma_f32_16x16x32_bf16((a), (b), (c), 0, 0, 0)
#define MFMA32(a, b, c) __builtin_amdgcn_mfma_f32_32x32x16_bf16((a), (b), (c), 0, 0, 0)

#define DIM 384
#define T1 3136   // 56*56
#define T2 784    // 28*28
#define T2P 832   // padded t for Vt columns
#define B_ 8
#define EPSV 1e-5f

__device__ __forceinline__ void gload_lds16(const bf16* g, bf16* l) {
  __builtin_amdgcn_global_load_lds(
      (const __attribute__((address_space(1))) void*)g,
      (__attribute__((address_space(3))) void*)l, 16, 0, 0);
}

__device__ __forceinline__ u32 pk2(float a, float b) {
  bf16x2 t = (bf16x2){(bf16)a, (bf16)b};
  return *reinterpret_cast<u32*>(&t);
}

// ---------------- fused depthwise convs + BN (q stride-1; k,v stride-2) + wcvt ------
__global__ void conv_fused_kernel(const float* __restrict__ x,
    const float* __restrict__ wqc, const float* __restrict__ gq, const float* __restrict__ bq,
    const float* __restrict__ mq, const float* __restrict__ vq,
    const float* __restrict__ wkc, const float* __restrict__ gk, const float* __restrict__ bk,
    const float* __restrict__ mk, const float* __restrict__ vk,
    const float* __restrict__ wvc, const float* __restrict__ gv, const float* __restrict__ bv,
    const float* __restrict__ mv, const float* __restrict__ vvv,
    bf16* __restrict__ qout, bf16* __restrict__ kout, bf16* __restrict__ vout,
    const float* __restrict__ w0, const float* __restrict__ w1,
    const float* __restrict__ w2, const float* __restrict__ w3,
    bf16* __restrict__ d0, bf16* __restrict__ d1,
    bf16* __restrict__ d2, bf16* __restrict__ d3) {
  int blk = blockIdx.x;
  int c = threadIdx.x;           // 0..383
  int gid = blk * DIM + c;
  if (gid < 147456) {            // folded weight conversion (first 384 blocks)
    d0[gid] = (bf16)w0[gid]; d1[gid] = (bf16)w1[gid];
    d2[gid] = (bf16)w2[gid]; d3[gid] = (bf16)w3[gid];
  }
  int xg = blk % 14;
  int y = (blk / 14) % 56;
  int b = blk / (14 * 56);
  int x0 = xg * 4;
  const float* xb = x + (size_t)b * T1 * DIM;
  float in[3][6];
#pragma unroll
  for (int r = 0; r < 3; ++r) {
    int yy = y + r - 1;
#pragma unroll
    for (int cc = 0; cc < 6; ++cc) {
      int xc = x0 + cc - 1;
      in[r][cc] = (yy >= 0 && yy < 56 && xc >= 0 && xc < 56)
                      ? xb[(yy * 56 + xc) * DIM + c] : 0.f;
    }
  }
  // q path
  {
    float wr[9];
#pragma unroll
    for (int i = 0; i < 9; ++i) wr[i] = wqc[c * 9 + i];
    float a = rsqrtf(vq[c] + EPSV) * gq[c];
    float bia = bq[c] - mq[c] * a;
#pragma unroll
    for (int p = 0; p < 4; ++p) {
      float s = 0.f;
#pragma unroll
      for (int r = 0; r < 3; ++r)
#pragma unroll
        for (int dx = 0; dx < 3; ++dx) s += in[r][p + dx] * wr[r * 3 + dx];
      qout[((size_t)b * T1 + y * 56 + x0 + p) * DIM + c] = (bf16)(s * a + bia);
    }
  }
  // kv path (block-uniform branch)
  if ((y & 1) == 0) {
    int y2 = y >> 1;
    float wk9[9], wv9[9];
#pragma unroll
    for (int i = 0; i < 9; ++i) { wk9[i] = wkc[c * 9 + i]; wv9[i] = wvc[c * 9 + i]; }
    float ak = rsqrtf(vk[c] + EPSV) * gk[c];
    float av = rsqrtf(vvv[c] + EPSV) * gv[c];
    float bik = bk[c] - mk[c] * ak;
    float biv = bv[c] - mv[c] * av;
#pragma unroll
    for (int p2 = 0; p2 < 2; ++p2) {
      float sk = 0.f, sv = 0.f;
#pragma unroll
      for (int r = 0; r < 3; ++r)
#pragma unroll
        for (int dx = 0; dx < 3; ++dx) {
          float xv = in[r][2 * p2 + dx];
          sk += xv * wk9[r * 3 + dx];
          sv += xv * wv9[r * 3 + dx];
        }
      size_t o = ((size_t)b * T2 + y2 * 28 + (x0 >> 1) + p2) * DIM + c;
      kout[o] = (bf16)(sk * ak + bik);
      vout[o] = (bf16)(sv * av + biv);
    }
  }
}

// ---------------- LDS-free GEMM: C[128,128] tile, operands direct from global ------
// R12: every staged variant (block-barrier 2-phase R0/R7, 8-wave 256-tile R10,
// barrier-free per-wave LDS R11) pinned at ~3000 cy/K-step with MfmaUtil 5-7.6%.
// The invariant was the global_load_lds + LDS round-trip on the critical path.
// Here BOTH operands are consumed directly from global in the exact MFMA fragment
// pattern: lane l16 reads 16 contiguous B at row (m0+..+l16), offset k0+quad*8
// (16B-aligned: row stride 768B). Same global bytes as staging (each element
// transits once per block), but NO LDS, NO barriers, NO waitcnt choreography —
// plain loads the compiler software-pipelines, one-step register double-buffer.
// W (288 KB) is L2-pinned across the 98-392 blocks that read it.
__device__ __forceinline__
void gemm_body(const bf16* A, const bf16* Bw, void* out, const float* bias,
               int mode, float scale, int m0, int n0) {
  int tid = threadIdx.x;
  int w = tid >> 6, lane = tid & 63;
  int wm = w >> 1, wn = w & 1;
  int l16 = lane & 15, quad = lane >> 4;
  floatx4 acc[4][4];
#pragma unroll
  for (int i = 0; i < 4; ++i)
#pragma unroll
    for (int j = 0; j < 4; ++j) acc[i][j] = (floatx4){0.f, 0.f, 0.f, 0.f};

  const bf16* ap[4];
  const bf16* bp[4];
#pragma unroll
  for (int i = 0; i < 4; ++i) {
    ap[i] = &A[(size_t)(m0 + wm * 64 + i * 16 + l16) * DIM + quad * 8];
    bp[i] = &Bw[(size_t)(n0 + wn * 64 + i * 16 + l16) * DIM + quad * 8];
  }

  bf16x8 af[2][4], bfr[2][4];
#pragma unroll
  for (int i = 0; i < 4; ++i) {
    af[0][i]  = *(const bf16x8*)(ap[i]);
    bfr[0][i] = *(const bf16x8*)(bp[i]);
  }
  const int NS = DIM / 32;  // 12
#pragma unroll
  for (int s = 0; s < NS; ++s) {
    const int cur = s & 1;                 // static after full unroll
    if (s + 1 < NS) {
      const int nk = (s + 1) * 32;
#pragma unroll
      for (int i = 0; i < 4; ++i) {
        af[cur ^ 1][i]  = *(const bf16x8*)(ap[i] + nk);
        bfr[cur ^ 1][i] = *(const bf16x8*)(bp[i] + nk);
      }
    }
#pragma unroll
    for (int i = 0; i < 4; ++i)
#pragma unroll
      for (int j = 0; j < 4; ++j)
        acc[i][j] = MFMA16(af[cur][i], bfr[cur][j], acc[i][j]);
  }
  // epilogue (R4-proven 16x16 C layout: col=lane&15, row=quad*4+rr)
#pragma unroll
  for (int i = 0; i < 4; ++i) {
#pragma unroll
    for (int j = 0; j < 4; ++j) {
#pragma unroll
      for (int rr = 0; rr < 4; ++rr) {
        int row = m0 + wm * 64 + i * 16 + quad * 4 + rr;
        int col = n0 + wn * 64 + j * 16 + l16;
        float v = acc[i][j][rr];
        if (mode == 3) {
          ((float*)out)[(size_t)row * DIM + col] = v + bias[col];
        } else if (mode == 2) {
          int b = row / T2;
          int t = row - b * T2;
          ((bf16*)out)[((size_t)b * DIM + col) * T2P + t] = (bf16)v;
        } else {
          ((bf16*)out)[(size_t)row * DIM + col] = (bf16)(v * scale);
        }
      }
    }
  }
}

// Q (588) + K (147) + V (147) tiles; XCD swizzle as R4 (proven harmless).
__global__ __launch_bounds__(256, 2)
void qkv_gemm_kernel(const bf16* q_act, const bf16* k_act, const bf16* v_act,
                     const bf16* wqb, const bf16* wkb, const bf16* wvb,
                     bf16* Qp, bf16* Kp, bf16* Vtp, float qscale) {
  int bx = blockIdx.x;
  int xp = bx & 7, j = bx >> 3;
  int t = (j / 3) * 24 + xp * 3 + (j % 3);
  if (t >= 882) return;
  const bf16 *A, *Bw; void* out; int mode, ti; float scale;
  if (t < 588)      { A = q_act; Bw = wqb; out = Qp;  mode = 1; scale = qscale; ti = t; }
  else if (t < 735) { A = k_act; Bw = wkb; out = Kp;  mode = 0; scale = 1.f; ti = t - 588; }
  else              { A = v_act; Bw = wvb; out = Vtp; mode = 2; scale = 1.f; ti = t - 735; }
  gemm_body(A, Bw, out, nullptr, mode, scale, (ti / 3) * 128, (ti % 3) * 128);
}

__global__ __launch_bounds__(256, 2)
void last_gemm_kernel(const bf16* A, const bf16* Bw, float* out, const float* bias) {
  int bx = blockIdx.x;
  int xp = bx & 7, j = bx >> 3;
  int t = (j / 3) * 24 + xp * 3 + (j % 3);
  if (t >= 588) return;
  gemm_body(A, Bw, out, bias, 3, 1.f, (t / 3) * 128, (t % 3) * 128);
}

// ---------------- flash attention, S^T/O^T form, 32x32 MFMA, in-register P --------
// R9 (proven): swapped QK^T lands P in the PV B-operand lane; exp2 in-reg ->
// bf16x2 pack -> __shfl_xor(32) -> PV. No P LDS. 16 KB LDS, launch_bounds(256,4).
__global__ __launch_bounds__(256, 4)
void attn_kernel(const bf16* __restrict__ Qp, const bf16* __restrict__ Kp,
                 const bf16* __restrict__ Vt, bf16* __restrict__ Ob) {
  __shared__ bf16 Kl[64 * 64];            // [t][d], chunk-XOR swizzled (8 KB)
  __shared__ bf16 Vl[64 * 64];            // [d][t], chunk-XOR swizzled (8 KB)
  int bx = blockIdx.x;
  int xcd = bx & 7, j = bx >> 3;
  int g = xcd + 8 * (j / 25);             // (b,h) group 0..47, fixed per XCD
  int qblk = j % 25;
  int h = g % 6;
  int b = g / 6;
  int tid = threadIdx.x, w = tid >> 6, lane = tid & 63;
  int l32 = lane & 31, hi = lane >> 5;
  int q0w = qblk * 128 + w * 32;

  // Q fragments, B-operand of 32x32x16: n=lane&31=q, k=hi*8+j -> d=kk*16+hi*8+j
  bf16x8 qf[4];
  {
    int qi = q0w + l32;
    qi = qi < T1 ? qi : T1 - 1;
    const bf16* qp = &Qp[((size_t)b * T1 + qi) * DIM + h * 64];
#pragma unroll
    for (int kk = 0; kk < 4; ++kk) qf[kk] = *(const bf16x8*)&qp[kk * 16 + hi * 8];
  }
  floatx16 oacc[2];
  oacc[0] = (floatx16)0.f;
  oacc[1] = (floatx16)0.f;
  float lsum = 0.f;

  int rsub = lane >> 3;
  int chnk = (lane & 7) ^ rsub;
  const bf16* kg0 = &Kp[((size_t)b * T2 + w * 16 + rsub) * DIM + h * 64 + chnk * 8];
  const bf16* kg1 = kg0 + (size_t)8 * DIM;
  const bf16* vg0 = &Vt[((size_t)b * DIM + h * 64 + w * 16 + rsub) * T2P + chnk * 8];
  const bf16* vg1 = vg0 + (size_t)8 * T2P;
  bf16* kl0 = &Kl[(w * 16) * 64];
  bf16* kl1 = &Kl[(w * 16 + 8) * 64];
  bf16* vl0 = &Vl[(w * 16) * 64];
  bf16* vl1 = &Vl[(w * 16 + 8) * 64];

  int key = lane & 7;                     // fragment-read swizzle key (= row&7)

  for (int it = 0; it < 12; ++it) {
    __syncthreads();                      // prev iter's tile reads done
    gload_lds16(kg0, kl0);
    gload_lds16(kg1, kl1);
    gload_lds16(vg0, vl0);
    gload_lds16(vg1, vl1);
    __syncthreads();                      // drains vmcnt: tiles ready
#pragma unroll
    for (int tt = 0; tt < 2; ++tt) {      // two 32-t tiles
      floatx16 s = (floatx16)0.f;
#pragma unroll
      for (int kk = 0; kk < 4; ++kk) {    // d = kk*16 + hi*8 + j
        bf16x8 kf = *(const bf16x8*)&Kl[(tt * 32 + l32) * 64 + ((kk * 2 + hi) ^ key) * 8];
        s = MFMA32(kf, qf[kk], s);
      }
      float e[16];
#pragma unroll
      for (int r = 0; r < 16; ++r) {
        e[r] = __builtin_amdgcn_exp2f(s[r]);
        lsum += e[r];
      }
#pragma unroll
      for (int kkl = 0; kkl < 2; ++kkl) {
        int r0 = kkl * 8;
        u32 pA = pk2(e[r0 + 0], e[r0 + 1]);
        u32 pB = pk2(e[r0 + 2], e[r0 + 3]);
        u32 pC = pk2(e[r0 + 4], e[r0 + 5]);
        u32 pD = pk2(e[r0 + 6], e[r0 + 7]);
        u32 sA = __shfl_xor(pA, 32);
        u32 sB = __shfl_xor(pB, 32);
        u32 sC = __shfl_xor(pC, 32);
        u32 sD = __shfl_xor(pD, 32);
        union { u32 u[4]; bf16x8 v; } pf;
        pf.u[0] = hi ? sC : pA;
        pf.u[1] = hi ? sD : pB;
        pf.u[2] = hi ? pC : sA;
        pf.u[3] = hi ? pD : sB;
        int kk = tt * 2 + kkl;            // t-chunk for V: t = kk*16 + hi*8 + j
#pragma unroll
        for (int dt = 0; dt < 2; ++dt) {
          bf16x8 vf = *(const bf16x8*)&Vl[(dt * 32 + l32) * 64 + ((kk * 2 + hi) ^ key) * 8];
          oacc[dt] = MFMA32(vf, pf.v, oacc[dt]);
        }
      }
    }
    kg0 += (size_t)64 * DIM; kg1 += (size_t)64 * DIM;
    vg0 += 64; vg1 += 64;
  }
  // tail: t 768..783 (16 rows land in reg group r0..7; clamped rows never consumed)
  {
    int tq = 768 + l32;
    tq = tq < T2 ? tq : T2 - 1;
    const bf16* kp2 = &Kp[((size_t)b * T2 + tq) * DIM + h * 64];
    floatx16 s = (floatx16)0.f;
#pragma unroll
    for (int kk = 0; kk < 4; ++kk) {
      bf16x8 kf = *(const bf16x8*)&kp2[kk * 16 + hi * 8];
      s = MFMA32(kf, qf[kk], s);
    }
    float e[8];
#pragma unroll
    for (int r = 0; r < 8; ++r) {
      e[r] = __builtin_amdgcn_exp2f(s[r]);
      lsum += e[r];
    }
    u32 pA = pk2(e[0], e[1]);
    u32 pB = pk2(e[2], e[3]);
    u32 pC = pk2(e[4], e[5]);
    u32 pD = pk2(e[6], e[7]);
    u32 sA = __shfl_xor(pA, 32);
    u32 sB = __shfl_xor(pB, 32);
    u32 sC = __shfl_xor(pC, 32);
    u32 sD = __shfl_xor(pD, 32);
    union { u32 u[4]; bf16x8 v; } pf;
    pf.u[0] = hi ? sC : pA;
    pf.u[1] = hi ? sD : pB;
    pf.u[2] = hi ? pC : sA;
    pf.u[3] = hi ? pD : sB;
#pragma unroll
    for (int dt = 0; dt < 2; ++dt) {
      const bf16* vp2 = &Vt[((size_t)b * DIM + h * 64 + dt * 32 + l32) * T2P + 768 + hi * 8];
      bf16x8 vf = *(const bf16x8*)vp2;
      oacc[dt] = MFMA32(vf, pf.v, oacc[dt]);
    }
  }
  // epilogue
  lsum += __shfl_xor(lsum, 32);
  float inv = 1.f / lsum;
  int qg = q0w + l32;
  if (qg < T1) {
    bf16* op = &Ob[((size_t)b * T1 + qg) * DIM + h * 64];
#pragma unroll
    for (int dt = 0; dt < 2; ++dt) {
#pragma unroll
      for (int gr = 0; gr < 4; ++gr) {
        bf16x4 ov = (bf16x4){(bf16)(oacc[dt][gr * 4 + 0] * inv),
                             (bf16)(oacc[dt][gr * 4 + 1] * inv),
                             (bf16)(oacc[dt][gr * 4 + 2] * inv),
                             (bf16)(oacc[dt][gr * 4 + 3] * inv)};
        *(bf16x4*)&op[dt * 32 + gr * 8 + hi * 4] = ov;
      }
    }
  }
}

// ---------------- launch ----------------
extern "C" void kernel_launch(void* const* d_in, const int* in_sizes, int n_in,
                              void* d_out, int out_size, void* d_ws, size_t ws_size,
                              hipStream_t stream) {
  (void)in_sizes; (void)n_in; (void)out_size; (void)ws_size;
  const float* x      = (const float*)d_in[0];
  const float* conv_q = (const float*)d_in[3];
  const float* bnq_s  = (const float*)d_in[4];
  const float* bnq_b  = (const float*)d_in[5];
  const float* bnq_m  = (const float*)d_in[6];
  const float* bnq_v  = (const float*)d_in[7];
  const float* conv_k = (const float*)d_in[8];
  const float* bnk_s  = (const float*)d_in[9];
  const float* bnk_b  = (const float*)d_in[10];
  const float* bnk_m  = (const float*)d_in[11];
  const float* bnk_v  = (const float*)d_in[12];
  const float* conv_v = (const float*)d_in[13];
  const float* bnv_s  = (const float*)d_in[14];
  const float* bnv_b  = (const float*)d_in[15];
  const float* bnv_m  = (const float*)d_in[16];
  const float* bnv_v  = (const float*)d_in[17];
  const float* wq     = (const float*)d_in[18];
  const float* wk     = (const float*)d_in[19];
  const float* wv     = (const float*)d_in[20];
  const float* wl     = (const float*)d_in[21];
  const float* b_last = (const float*)d_in[22];

  char* ws = (char*)d_ws;
  bf16* q_act = (bf16*)(ws + 0);               // 19267584; reused as attention output
  bf16* k_act = (bf16*)(ws + 19267584);        // 4816896
  bf16* v_act = (bf16*)(ws + 24084480);        // 4816896
  bf16* Qp    = (bf16*)(ws + 28901376);        // 19267584 (pre-scaled by SCALE*log2e)
  bf16* Kp    = (bf16*)(ws + 48168960);        // 4816896
  bf16* Vtp   = (bf16*)(ws + 52985856);        // 8*384*832*2 = 5111808  [B][384][T2P]
  bf16* wqb   = (bf16*)(ws + 58097664);        // 294912 each, x4
  bf16* wkb   = wqb + 147456;
  bf16* wvb   = wkb + 147456;
  bf16* wlb   = wvb + 147456;

  const float QSCALE = 0.05103103630798288f * 1.4426950408889634f;  // 384^-0.5 * log2e

  conv_fused_kernel<<<B_ * 56 * 14, DIM, 0, stream>>>(
      x,
      conv_q, bnq_s, bnq_b, bnq_m, bnq_v,
      conv_k, bnk_s, bnk_b, bnk_m, bnk_v,
      conv_v, bnv_s, bnv_b, bnv_m, bnv_v,
      q_act, k_act, v_act,
      wq, wk, wv, wl, wqb, wkb, wvb, wlb);

  qkv_gemm_kernel<<<888, 256, 0, stream>>>(q_act, k_act, v_act, wqb, wkb, wvb,
                                           Qp, Kp, Vtp, QSCALE);

  attn_kernel<<<25 * 6 * B_, 256, 0, stream>>>(Qp, Kp, Vtp, q_act);

  last_gemm_kernel<<<600, 256, 0, stream>>>(q_act, wlb, (float*)d_out, b_last);
}

// Round 8
// 270.450 us; speedup vs baseline: 1.1238x; 1.0621x over previous
//
#include <hip/hip_runtime.h>
#include <hip/hip_bf16.h>

typedef __bf16 bf16;
typedef __attribute__((ext_vector_type(8))) __bf16 bf16x8;
typedef __attribute__((ext_vector_type(4))) __bf16 bf16x4;
typedef __attribute__((ext_vector_type(2))) __bf16 bf16x2;
typedef __attribute__((ext_vector_type(4))) float floatx4;
typedef __attribute__((ext_vector_type(16))) float floatx16;
typedef unsigned int u32;

#define MFMA16(a, b, c) __builtin_amdgcn_mfma_f32_16x16x32_bf16((a), (b), (c), 0, 0, 0)
#define MFMA32(a, b, c) __builtin_amdgcn_mfma_f32_32x32x16_bf16((a), (b), (c), 0, 0, 0)

#define DIM 384
#define T1 3136   // 56*56
#define T2 784    // 28*28
#define T2P 832   // padded t for Vt columns
#define B_ 8
#define EPSV 1e-5f
// 384^-0.5 * log2e, folded into the Wq bf16 conversion (Q-GEMM fused into attn)
#define QS (0.05103103630798288f * 1.4426950408889634f)

__device__ __forceinline__ void gload_lds16(const bf16* g, bf16* l) {
  __builtin_amdgcn_global_load_lds(
      (const __attribute__((address_space(1))) void*)g,
      (__attribute__((address_space(3))) void*)l, 16, 0, 0);
}

__device__ __forceinline__ u32 pk2(float a, float b) {
  bf16x2 t = (bf16x2){(bf16)a, (bf16)b};
  return *reinterpret_cast<u32*>(&t);
}

// ---------------- fused depthwise convs + BN (q stride-1; k,v stride-2) + wcvt ------
__global__ void conv_fused_kernel(const float* __restrict__ x,
    const float* __restrict__ wqc, const float* __restrict__ gq, const float* __restrict__ bq,
    const float* __restrict__ mq, const float* __restrict__ vq,
    const float* __restrict__ wkc, const float* __restrict__ gk, const float* __restrict__ bk,
    const float* __restrict__ mk, const float* __restrict__ vk,
    const float* __restrict__ wvc, const float* __restrict__ gv, const float* __restrict__ bv,
    const float* __restrict__ mv, const float* __restrict__ vvv,
    bf16* __restrict__ qout, bf16* __restrict__ kout, bf16* __restrict__ vout,
    const float* __restrict__ w0, const float* __restrict__ w1,
    const float* __restrict__ w2, const float* __restrict__ w3,
    bf16* __restrict__ d0, bf16* __restrict__ d1,
    bf16* __restrict__ d2, bf16* __restrict__ d3) {
  int blk = blockIdx.x;
  int c = threadIdx.x;           // 0..383
  int gid = blk * DIM + c;
  if (gid < 147456) {            // folded weight conversion (first 384 blocks)
    d0[gid] = (bf16)(w0[gid] * QS);       // Wq pre-scaled: fused Q-GEMM needs no scale
    d1[gid] = (bf16)w1[gid];
    d2[gid] = (bf16)w2[gid];
    d3[gid] = (bf16)w3[gid];
  }
  int xg = blk % 14;
  int y = (blk / 14) % 56;
  int b = blk / (14 * 56);
  int x0 = xg * 4;
  const float* xb = x + (size_t)b * T1 * DIM;
  float in[3][6];
#pragma unroll
  for (int r = 0; r < 3; ++r) {
    int yy = y + r - 1;
#pragma unroll
    for (int cc = 0; cc < 6; ++cc) {
      int xc = x0 + cc - 1;
      in[r][cc] = (yy >= 0 && yy < 56 && xc >= 0 && xc < 56)
                      ? xb[(yy * 56 + xc) * DIM + c] : 0.f;
    }
  }
  // q path
  {
    float wr[9];
#pragma unroll
    for (int i = 0; i < 9; ++i) wr[i] = wqc[c * 9 + i];
    float a = rsqrtf(vq[c] + EPSV) * gq[c];
    float bia = bq[c] - mq[c] * a;
#pragma unroll
    for (int p = 0; p < 4; ++p) {
      float s = 0.f;
#pragma unroll
      for (int r = 0; r < 3; ++r)
#pragma unroll
        for (int dx = 0; dx < 3; ++dx) s += in[r][p + dx] * wr[r * 3 + dx];
      qout[((size_t)b * T1 + y * 56 + x0 + p) * DIM + c] = (bf16)(s * a + bia);
    }
  }
  // kv path (block-uniform branch)
  if ((y & 1) == 0) {
    int y2 = y >> 1;
    float wk9[9], wv9[9];
#pragma unroll
    for (int i = 0; i < 9; ++i) { wk9[i] = wkc[c * 9 + i]; wv9[i] = wvc[c * 9 + i]; }
    float ak = rsqrtf(vk[c] + EPSV) * gk[c];
    float av = rsqrtf(vvv[c] + EPSV) * gv[c];
    float bik = bk[c] - mk[c] * ak;
    float biv = bv[c] - mv[c] * av;
#pragma unroll
    for (int p2 = 0; p2 < 2; ++p2) {
      float sk = 0.f, sv = 0.f;
#pragma unroll
      for (int r = 0; r < 3; ++r)
#pragma unroll
        for (int dx = 0; dx < 3; ++dx) {
          float xv = in[r][2 * p2 + dx];
          sk += xv * wk9[r * 3 + dx];
          sv += xv * wv9[r * 3 + dx];
        }
      size_t o = ((size_t)b * T2 + y2 * 28 + (x0 >> 1) + p2) * DIM + c;
      kout[o] = (bf16)(sk * ak + bik);
      vout[o] = (bf16)(sv * av + biv);
    }
  }
}

// ---------------- shared GEMM body: C[128,128] tile of A[M,384] @ W[384,384]^T ------
// R4-proven structure (R7 2-phase pipeline). Used for K/V projections + last GEMM.
#define BK 32
#define BUFSZ (128 * BK)
__device__ __forceinline__
void gemm_body(const bf16* A, const bf16* Bw, void* out, const float* bias,
               int mode, int m0, int n0, bf16* Al, bf16* Bl) {
  int tid = threadIdx.x;
  int w = tid >> 6, lane = tid & 63;
  int wm = w >> 1, wn = w & 1;
  int l16 = lane & 15, quad = lane >> 4;
  floatx4 acc[4][4];
#pragma unroll
  for (int i = 0; i < 4; ++i)
#pragma unroll
    for (int j = 0; j < 4; ++j) acc[i][j] = (floatx4){0.f, 0.f, 0.f, 0.f};

  int srow = w * 32 + (lane >> 2);
  int scol = (lane & 3) * 8;
  const bf16* ag0 = &A[(size_t)(m0 + srow) * DIM + scol];
  const bf16* ag1 = ag0 + (size_t)16 * DIM;
  const bf16* bg0 = &Bw[(size_t)(n0 + srow) * DIM + scol];
  const bf16* bg1 = bg0 + (size_t)16 * DIM;
  int lofs0 = (w * 32) * BK;
  int lofs1 = (w * 32 + 16) * BK;

  gload_lds16(ag0, Al + lofs0);
  gload_lds16(ag1, Al + lofs1);
  gload_lds16(bg0, Bl + lofs0);
  gload_lds16(bg1, Bl + lofs1);

  const int NS = DIM / BK;  // 12
#pragma unroll
  for (int s = 0; s < NS; ++s) {
    const int cb = s & 1;
    if (s + 1 < NS) {
      const int k = (s + 1) * BK;
      bf16* an = Al + (cb ^ 1) * BUFSZ;
      bf16* bn = Bl + (cb ^ 1) * BUFSZ;
      gload_lds16(ag0 + k, an + lofs0);
      gload_lds16(ag1 + k, an + lofs1);
      gload_lds16(bg0 + k, bn + lofs0);
      gload_lds16(bg1 + k, bn + lofs1);
      asm volatile("s_waitcnt vmcnt(4)" ::: "memory");
    } else {
      asm volatile("s_waitcnt vmcnt(0)" ::: "memory");
    }
    __builtin_amdgcn_s_barrier();
    const bf16* Ac = Al + cb * BUFSZ;
    const bf16* Bc = Bl + cb * BUFSZ;
    bf16x8 af[4], bfr[4];
#pragma unroll
    for (int i = 0; i < 4; ++i) {
      af[i]  = *(const bf16x8*)&Ac[(wm * 64 + i * 16 + l16) * BK + quad * 8];
      bfr[i] = *(const bf16x8*)&Bc[(wn * 64 + i * 16 + l16) * BK + quad * 8];
    }
#pragma unroll
    for (int i = 0; i < 4; ++i)
#pragma unroll
      for (int j = 0; j < 4; ++j)
        acc[i][j] = MFMA16(af[i], bfr[j], acc[i][j]);
    asm volatile("s_waitcnt lgkmcnt(0)" ::: "memory");
    __builtin_amdgcn_s_barrier();
  }
#pragma unroll
  for (int i = 0; i < 4; ++i) {
#pragma unroll
    for (int j = 0; j < 4; ++j) {
#pragma unroll
      for (int rr = 0; rr < 4; ++rr) {
        int row = m0 + wm * 64 + i * 16 + quad * 4 + rr;
        int col = n0 + wn * 64 + j * 16 + l16;
        float v = acc[i][j][rr];
        if (mode == 3) {
          ((float*)out)[(size_t)row * DIM + col] = v + bias[col];
        } else if (mode == 2) {
          int b = row / T2;
          int t = row - b * T2;
          ((bf16*)out)[((size_t)b * DIM + col) * T2P + t] = (bf16)v;
        } else {
          ((bf16*)out)[(size_t)row * DIM + col] = (bf16)v;
        }
      }
    }
  }
}

// K (147) + V (147) tiles only (Q-projection fused into attn). 296 = 8*37 grid,
// bijective XCD chunking.
__global__ __launch_bounds__(256)
void kv_gemm_kernel(const bf16* k_act, const bf16* v_act,
                    const bf16* wkb, const bf16* wvb,
                    bf16* Kp, bf16* Vtp) {
  __shared__ bf16 Al[2 * BUFSZ];
  __shared__ bf16 Bl[2 * BUFSZ];
  int bx = blockIdx.x;
  int t = (bx & 7) * 37 + (bx >> 3);
  if (t >= 294) return;
  const bf16 *A, *Bw; void* out; int mode, ti;
  if (t < 147) { A = k_act; Bw = wkb; out = Kp;  mode = 0; ti = t; }
  else         { A = v_act; Bw = wvb; out = Vtp; mode = 2; ti = t - 147; }
  gemm_body(A, Bw, out, nullptr, mode, (ti / 3) * 128, (ti % 3) * 128, Al, Bl);
}

__global__ __launch_bounds__(256)
void last_gemm_kernel(const bf16* A, const bf16* Bw, float* out, const float* bias) {
  __shared__ bf16 Al[2 * BUFSZ];
  __shared__ bf16 Bl[2 * BUFSZ];
  int bx = blockIdx.x;
  int xp = bx & 7, j = bx >> 3;
  int t = (j / 3) * 24 + xp * 3 + (j % 3);
  if (t >= 588) return;
  gemm_body(A, Bw, out, bias, 3, (t / 3) * 128, (t % 3) * 128, Al, Bl);
}

// ---------------- flash attention, S^T/O^T form, 32x32 MFMA, in-register P --------
// R9 (proven): swapped QK^T lands P in the PV B-operand lane; exp2 in-reg ->
// bf16x2 pack -> __shfl_xor(32) -> PV. No P LDS.
// R13: Q-projection FUSED: each wave computes its own 32x64 Q-slice from q_act
// (B-operand rows, same addressing R9 used for Qp) x Wq-slice (A-operand rows,
// 288 KB L2-resident across all 1200 blocks; QSCALE pre-folded into wqb).
// The C->B-frag transform is R9's proven P-transform with d<->t. Deletes the
// 588-tile Q-GEMM (~35 us) and 38 MB of Qp write+read traffic.
__global__ __launch_bounds__(256, 4)
void attn_kernel(const bf16* __restrict__ q_act, const bf16* __restrict__ Wq,
                 const bf16* __restrict__ Kp, const bf16* __restrict__ Vt,
                 bf16* __restrict__ Ob) {
  __shared__ bf16 Kl[64 * 64];            // [t][d], chunk-XOR swizzled (8 KB)
  __shared__ bf16 Vl[64 * 64];            // [d][t], chunk-XOR swizzled (8 KB)
  int bx = blockIdx.x;
  int xcd = bx & 7, j = bx >> 3;
  int g = xcd + 8 * (j / 25);             // (b,h) group 0..47, fixed per XCD
  int qblk = j % 25;
  int h = g % 6;
  int b = g / 6;
  int tid = threadIdx.x, w = tid >> 6, lane = tid & 63;
  int l32 = lane & 31, hi = lane >> 5;
  int q0w = qblk * 128 + w * 32;

  // ---- fused Q projection: Qt[d][q] = sum_c Wq[h*64+d][c] * q_act[q][c] ----
  // A-frag rows = Wq (m=d), B-frag rows = q_act (n=q=l32). C: col=q, row=d with
  // d = dt*32 + (r&3)+8*(r>>2)+4*hi  ->  transform to qf[kk] (d = kk*16+hi*8+j).
  bf16x8 qf[4];
  {
    int qi = q0w + l32;
    qi = qi < T1 ? qi : T1 - 1;          // clamped rows: per-lane garbage, never stored
    const bf16* aq = &q_act[((size_t)b * T1 + qi) * DIM];
    const bf16* wp = &Wq[(size_t)(h * 64 + l32) * DIM];
    floatx16 qacc0 = (floatx16)0.f, qacc1 = (floatx16)0.f;
#pragma unroll
    for (int ks = 0; ks < 24; ++ks) {
      bf16x8 bq  = *(const bf16x8*)&aq[ks * 16 + hi * 8];
      bf16x8 w0f = *(const bf16x8*)&wp[ks * 16 + hi * 8];
      bf16x8 w1f = *(const bf16x8*)&wp[(size_t)32 * DIM + ks * 16 + hi * 8];
      qacc0 = MFMA32(w0f, bq, qacc0);
      qacc1 = MFMA32(w1f, bq, qacc1);
    }
#pragma unroll
    for (int dt = 0; dt < 2; ++dt) {
      float e[16];
#pragma unroll
      for (int r = 0; r < 16; ++r) e[r] = dt ? qacc1[r] : qacc0[r];
#pragma unroll
      for (int kkl = 0; kkl < 2; ++kkl) {
        int r0 = kkl * 8;
        u32 pA = pk2(e[r0 + 0], e[r0 + 1]);
        u32 pB = pk2(e[r0 + 2], e[r0 + 3]);
        u32 pC = pk2(e[r0 + 4], e[r0 + 5]);
        u32 pD = pk2(e[r0 + 6], e[r0 + 7]);
        u32 sA = __shfl_xor(pA, 32);
        u32 sB = __shfl_xor(pB, 32);
        u32 sC = __shfl_xor(pC, 32);
        u32 sD = __shfl_xor(pD, 32);
        union { u32 u[4]; bf16x8 v; } pf;
        pf.u[0] = hi ? sC : pA;
        pf.u[1] = hi ? sD : pB;
        pf.u[2] = hi ? pC : sA;
        pf.u[3] = hi ? pD : sB;
        qf[dt * 2 + kkl] = pf.v;
      }
    }
  }

  floatx16 oacc[2];
  oacc[0] = (floatx16)0.f;
  oacc[1] = (floatx16)0.f;
  float lsum = 0.f;

  int rsub = lane >> 3;
  int chnk = (lane & 7) ^ rsub;
  const bf16* kg0 = &Kp[((size_t)b * T2 + w * 16 + rsub) * DIM + h * 64 + chnk * 8];
  const bf16* kg1 = kg0 + (size_t)8 * DIM;
  const bf16* vg0 = &Vt[((size_t)b * DIM + h * 64 + w * 16 + rsub) * T2P + chnk * 8];
  const bf16* vg1 = vg0 + (size_t)8 * T2P;
  bf16* kl0 = &Kl[(w * 16) * 64];
  bf16* kl1 = &Kl[(w * 16 + 8) * 64];
  bf16* vl0 = &Vl[(w * 16) * 64];
  bf16* vl1 = &Vl[(w * 16 + 8) * 64];

  int key = lane & 7;                     // fragment-read swizzle key (= row&7)

  for (int it = 0; it < 12; ++it) {
    __syncthreads();                      // prev iter's tile reads done
    gload_lds16(kg0, kl0);
    gload_lds16(kg1, kl1);
    gload_lds16(vg0, vl0);
    gload_lds16(vg1, vl1);
    __syncthreads();                      // drains vmcnt: tiles ready
#pragma unroll
    for (int tt = 0; tt < 2; ++tt) {      // two 32-t tiles
      floatx16 s = (floatx16)0.f;
#pragma unroll
      for (int kk = 0; kk < 4; ++kk) {    // d = kk*16 + hi*8 + j
        bf16x8 kf = *(const bf16x8*)&Kl[(tt * 32 + l32) * 64 + ((kk * 2 + hi) ^ key) * 8];
        s = MFMA32(kf, qf[kk], s);
      }
      float e[16];
#pragma unroll
      for (int r = 0; r < 16; ++r) {
        e[r] = __builtin_amdgcn_exp2f(s[r]);
        lsum += e[r];
      }
#pragma unroll
      for (int kkl = 0; kkl < 2; ++kkl) {
        int r0 = kkl * 8;
        u32 pA = pk2(e[r0 + 0], e[r0 + 1]);
        u32 pB = pk2(e[r0 + 2], e[r0 + 3]);
        u32 pC = pk2(e[r0 + 4], e[r0 + 5]);
        u32 pD = pk2(e[r0 + 6], e[r0 + 7]);
        u32 sA = __shfl_xor(pA, 32);
        u32 sB = __shfl_xor(pB, 32);
        u32 sC = __shfl_xor(pC, 32);
        u32 sD = __shfl_xor(pD, 32);
        union { u32 u[4]; bf16x8 v; } pf;
        pf.u[0] = hi ? sC : pA;
        pf.u[1] = hi ? sD : pB;
        pf.u[2] = hi ? pC : sA;
        pf.u[3] = hi ? pD : sB;
        int kk = tt * 2 + kkl;            // t-chunk for V: t = kk*16 + hi*8 + j
#pragma unroll
        for (int dt = 0; dt < 2; ++dt) {
          bf16x8 vf = *(const bf16x8*)&Vl[(dt * 32 + l32) * 64 + ((kk * 2 + hi) ^ key) * 8];
          oacc[dt] = MFMA32(vf, pf.v, oacc[dt]);
        }
      }
    }
    kg0 += (size_t)64 * DIM; kg1 += (size_t)64 * DIM;
    vg0 += 64; vg1 += 64;
  }
  // tail: t 768..783 (16 rows land in reg group r0..7; clamped rows never consumed)
  {
    int tq = 768 + l32;
    tq = tq < T2 ? tq : T2 - 1;
    const bf16* kp2 = &Kp[((size_t)b * T2 + tq) * DIM + h * 64];
    floatx16 s = (floatx16)0.f;
#pragma unroll
    for (int kk = 0; kk < 4; ++kk) {
      bf16x8 kf = *(const bf16x8*)&kp2[kk * 16 + hi * 8];
      s = MFMA32(kf, qf[kk], s);
    }
    float e[8];
#pragma unroll
    for (int r = 0; r < 8; ++r) {
      e[r] = __builtin_amdgcn_exp2f(s[r]);
      lsum += e[r];
    }
    u32 pA = pk2(e[0], e[1]);
    u32 pB = pk2(e[2], e[3]);
    u32 pC = pk2(e[4], e[5]);
    u32 pD = pk2(e[6], e[7]);
    u32 sA = __shfl_xor(pA, 32);
    u32 sB = __shfl_xor(pB, 32);
    u32 sC = __shfl_xor(pC, 32);
    u32 sD = __shfl_xor(pD, 32);
    union { u32 u[4]; bf16x8 v; } pf;
    pf.u[0] = hi ? sC : pA;
    pf.u[1] = hi ? sD : pB;
    pf.u[2] = hi ? pC : sA;
    pf.u[3] = hi ? pD : sB;
#pragma unroll
    for (int dt = 0; dt < 2; ++dt) {
      const bf16* vp2 = &Vt[((size_t)b * DIM + h * 64 + dt * 32 + l32) * T2P + 768 + hi * 8];
      bf16x8 vf = *(const bf16x8*)vp2;
      oacc[dt] = MFMA32(vf, pf.v, oacc[dt]);
    }
  }
  // epilogue
  lsum += __shfl_xor(lsum, 32);
  float inv = 1.f / lsum;
  int qg = q0w + l32;
  if (qg < T1) {
    bf16* op = &Ob[((size_t)b * T1 + qg) * DIM + h * 64];
#pragma unroll
    for (int dt = 0; dt < 2; ++dt) {
#pragma unroll
      for (int gr = 0; gr < 4; ++gr) {
        bf16x4 ov = (bf16x4){(bf16)(oacc[dt][gr * 4 + 0] * inv),
                             (bf16)(oacc[dt][gr * 4 + 1] * inv),
                             (bf16)(oacc[dt][gr * 4 + 2] * inv),
                             (bf16)(oacc[dt][gr * 4 + 3] * inv)};
        *(bf16x4*)&op[dt * 32 + gr * 8 + hi * 4] = ov;
      }
    }
  }
}

// ---------------- launch ----------------
extern "C" void kernel_launch(void* const* d_in, const int* in_sizes, int n_in,
                              void* d_out, int out_size, void* d_ws, size_t ws_size,
                              hipStream_t stream) {
  (void)in_sizes; (void)n_in; (void)out_size; (void)ws_size;
  const float* x      = (const float*)d_in[0];
  const float* conv_q = (const float*)d_in[3];
  const float* bnq_s  = (const float*)d_in[4];
  const float* bnq_b  = (const float*)d_in[5];
  const float* bnq_m  = (const float*)d_in[6];
  const float* bnq_v  = (const float*)d_in[7];
  const float* conv_k = (const float*)d_in[8];
  const float* bnk_s  = (const float*)d_in[9];
  const float* bnk_b  = (const float*)d_in[10];
  const float* bnk_m  = (const float*)d_in[11];
  const float* bnk_v  = (const float*)d_in[12];
  const float* conv_v = (const float*)d_in[13];
  const float* bnv_s  = (const float*)d_in[14];
  const float* bnv_b  = (const float*)d_in[15];
  const float* bnv_m  = (const float*)d_in[16];
  const float* bnv_v  = (const float*)d_in[17];
  const float* wq     = (const float*)d_in[18];
  const float* wk     = (const float*)d_in[19];
  const float* wv     = (const float*)d_in[20];
  const float* wl     = (const float*)d_in[21];
  const float* b_last = (const float*)d_in[22];

  char* ws = (char*)d_ws;
  bf16* q_act = (bf16*)(ws + 0);               // 19267584; reused as attention output
  bf16* k_act = (bf16*)(ws + 19267584);        // 4816896
  bf16* v_act = (bf16*)(ws + 24084480);        // 4816896
  // (Qp region at +28901376 now unused: Q-projection fused into attn)
  bf16* Kp    = (bf16*)(ws + 48168960);        // 4816896
  bf16* Vtp   = (bf16*)(ws + 52985856);        // 8*384*832*2 = 5111808  [B][384][T2P]
  bf16* wqb   = (bf16*)(ws + 58097664);        // 294912 each, x4; wqb pre-scaled by QS
  bf16* wkb   = wqb + 147456;
  bf16* wvb   = wkb + 147456;
  bf16* wlb   = wvb + 147456;

  conv_fused_kernel<<<B_ * 56 * 14, DIM, 0, stream>>>(
      x,
      conv_q, bnq_s, bnq_b, bnq_m, bnq_v,
      conv_k, bnk_s, bnk_b, bnk_m, bnk_v,
      conv_v, bnv_s, bnv_b, bnv_m, bnv_v,
      q_act, k_act, v_act,
      wq, wk, wv, wl, wqb, wkb, wvb, wlb);

  kv_gemm_kernel<<<296, 256, 0, stream>>>(k_act, v_act, wkb, wvb, Kp, Vtp);

  attn_kernel<<<25 * 6 * B_, 256, 0, stream>>>(q_act, wqb, Kp, Vtp, q_act);

  last_gemm_kernel<<<600, 256, 0, stream>>>(q_act, wlb, (float*)d_out, b_last);
}

// Round 9
// 235.585 us; speedup vs baseline: 1.2901x; 1.1480x over previous
//
#include <hip/hip_runtime.h>
#include <hip/hip_bf16.h>

typedef __bf16 bf16;
typedef __attribute__((ext_vector_type(8))) __bf16 bf16x8;
typedef __attribute__((ext_vector_type(4))) __bf16 bf16x4;
typedef __attribute__((ext_vector_type(2))) __bf16 bf16x2;
typedef __attribute__((ext_vector_type(4))) float floatx4;
typedef __attribute__((ext_vector_type(16))) float floatx16;
typedef unsigned int u32;

#define MFMA16(a, b, c) __builtin_amdgcn_mfma_f32_16x16x32_bf16((a), (b), (c), 0, 0, 0)
#define MFMA32(a, b, c) __builtin_amdgcn_mfma_f32_32x32x16_bf16((a), (b), (c), 0, 0, 0)

#define DIM 384
#define T1 3136   // 56*56
#define T2 784    // 28*28
#define T2P 832   // padded t for Vt columns
#define B_ 8
#define EPSV 1e-5f

__device__ __forceinline__ void gload_lds16(const bf16* g, bf16* l) {
  __builtin_amdgcn_global_load_lds(
      (const __attribute__((address_space(1))) void*)g,
      (__attribute__((address_space(3))) void*)l, 16, 0, 0);
}

__device__ __forceinline__ u32 pk2(float a, float b) {
  bf16x2 t = (bf16x2){(bf16)a, (bf16)b};
  return *reinterpret_cast<u32*>(&t);
}

// ---------------- fused depthwise convs + BN + wcvt, 4x4 spatial tile --------------
// R14: 4x4 output tile per block (was 1x4): halo in[6][6] = 2.25 x-loads/output
// (was 4.5) -> x L2/L3 traffic 173->87 MB; weight re-reads 172->65 MB; kv path
// (2x2 outputs, y0 always even) runs in every block - no parity divergence.
// Grid 1568 = 8*14*14 blocks x 384 threads.
__global__ void conv_fused_kernel(const float* __restrict__ x,
    const float* __restrict__ wqc, const float* __restrict__ gq, const float* __restrict__ bq,
    const float* __restrict__ mq, const float* __restrict__ vq,
    const float* __restrict__ wkc, const float* __restrict__ gk, const float* __restrict__ bk,
    const float* __restrict__ mk, const float* __restrict__ vk,
    const float* __restrict__ wvc, const float* __restrict__ gv, const float* __restrict__ bv,
    const float* __restrict__ mv, const float* __restrict__ vvv,
    bf16* __restrict__ qout, bf16* __restrict__ kout, bf16* __restrict__ vout,
    const float* __restrict__ w0, const float* __restrict__ w1,
    const float* __restrict__ w2, const float* __restrict__ w3,
    bf16* __restrict__ d0, bf16* __restrict__ d1,
    bf16* __restrict__ d2, bf16* __restrict__ d3) {
  int blk = blockIdx.x;
  int c = threadIdx.x;           // 0..383
  int gid = blk * DIM + c;
  if (gid < 147456) {            // folded weight conversion (first 384 blocks)
    d0[gid] = (bf16)w0[gid]; d1[gid] = (bf16)w1[gid];
    d2[gid] = (bf16)w2[gid]; d3[gid] = (bf16)w3[gid];
  }
  int xg = blk % 14;
  int yg = (blk / 14) % 14;
  int b = blk / 196;
  int x0 = xg * 4, y0 = yg * 4;
  const float* xb = x + (size_t)b * T1 * DIM;
  float in[6][6];
#pragma unroll
  for (int r = 0; r < 6; ++r) {
    int yy = y0 + r - 1;
#pragma unroll
    for (int cc = 0; cc < 6; ++cc) {
      int xc = x0 + cc - 1;
      in[r][cc] = (yy >= 0 && yy < 56 && xc >= 0 && xc < 56)
                      ? xb[(yy * 56 + xc) * DIM + c] : 0.f;
    }
  }
  // q path: 4x4 outputs
  {
    float wr[9];
#pragma unroll
    for (int i = 0; i < 9; ++i) wr[i] = wqc[c * 9 + i];
    float a = rsqrtf(vq[c] + EPSV) * gq[c];
    float bia = bq[c] - mq[c] * a;
#pragma unroll
    for (int py = 0; py < 4; ++py) {
#pragma unroll
      for (int px = 0; px < 4; ++px) {
        float s = 0.f;
#pragma unroll
        for (int r = 0; r < 3; ++r)
#pragma unroll
          for (int dx = 0; dx < 3; ++dx) s += in[py + r][px + dx] * wr[r * 3 + dx];
        qout[((size_t)b * T1 + (y0 + py) * 56 + x0 + px) * DIM + c] = (bf16)(s * a + bia);
      }
    }
  }
  // kv path: 2x2 stride-2 outputs (y0, x0 even)
  {
    float wk9[9], wv9[9];
#pragma unroll
    for (int i = 0; i < 9; ++i) { wk9[i] = wkc[c * 9 + i]; wv9[i] = wvc[c * 9 + i]; }
    float ak = rsqrtf(vk[c] + EPSV) * gk[c];
    float av = rsqrtf(vvv[c] + EPSV) * gv[c];
    float bik = bk[c] - mk[c] * ak;
    float biv = bv[c] - mv[c] * av;
#pragma unroll
    for (int py = 0; py < 2; ++py) {
#pragma unroll
      for (int px = 0; px < 2; ++px) {
        float sk = 0.f, sv = 0.f;
#pragma unroll
        for (int r = 0; r < 3; ++r)
#pragma unroll
          for (int dx = 0; dx < 3; ++dx) {
            float xv = in[2 * py + r][2 * px + dx];
            sk += xv * wk9[r * 3 + dx];
            sv += xv * wv9[r * 3 + dx];
          }
        size_t o = ((size_t)b * T2 + (y0 / 2 + py) * 28 + (x0 / 2 + px)) * DIM + c;
        kout[o] = (bf16)(sk * ak + bik);
        vout[o] = (bf16)(sv * av + biv);
      }
    }
  }
}

// ---------------- shared GEMM body: C[128,128] tile of A[M,384] @ W[384,384]^T ------
// R7 2-phase pipeline (best measured: 247.8 us config).
#define BK 32
#define BUFSZ (128 * BK)
__device__ __forceinline__
void gemm_body(const bf16* A, const bf16* Bw, void* out, const float* bias,
               int mode, float scale, int m0, int n0, bf16* Al, bf16* Bl) {
  int tid = threadIdx.x;
  int w = tid >> 6, lane = tid & 63;
  int wm = w >> 1, wn = w & 1;
  int l16 = lane & 15, quad = lane >> 4;
  floatx4 acc[4][4];
#pragma unroll
  for (int i = 0; i < 4; ++i)
#pragma unroll
    for (int j = 0; j < 4; ++j) acc[i][j] = (floatx4){0.f, 0.f, 0.f, 0.f};

  int srow = w * 32 + (lane >> 2);
  int scol = (lane & 3) * 8;
  const bf16* ag0 = &A[(size_t)(m0 + srow) * DIM + scol];
  const bf16* ag1 = ag0 + (size_t)16 * DIM;
  const bf16* bg0 = &Bw[(size_t)(n0 + srow) * DIM + scol];
  const bf16* bg1 = bg0 + (size_t)16 * DIM;
  int lofs0 = (w * 32) * BK;
  int lofs1 = (w * 32 + 16) * BK;

  gload_lds16(ag0, Al + lofs0);
  gload_lds16(ag1, Al + lofs1);
  gload_lds16(bg0, Bl + lofs0);
  gload_lds16(bg1, Bl + lofs1);

  const int NS = DIM / BK;  // 12
#pragma unroll
  for (int s = 0; s < NS; ++s) {
    const int cb = s & 1;
    if (s + 1 < NS) {
      const int k = (s + 1) * BK;
      bf16* an = Al + (cb ^ 1) * BUFSZ;
      bf16* bn = Bl + (cb ^ 1) * BUFSZ;
      gload_lds16(ag0 + k, an + lofs0);
      gload_lds16(ag1 + k, an + lofs1);
      gload_lds16(bg0 + k, bn + lofs0);
      gload_lds16(bg1 + k, bn + lofs1);
      asm volatile("s_waitcnt vmcnt(4)" ::: "memory");
    } else {
      asm volatile("s_waitcnt vmcnt(0)" ::: "memory");
    }
    __builtin_amdgcn_s_barrier();
    const bf16* Ac = Al + cb * BUFSZ;
    const bf16* Bc = Bl + cb * BUFSZ;
    bf16x8 af[4], bfr[4];
#pragma unroll
    for (int i = 0; i < 4; ++i) {
      af[i]  = *(const bf16x8*)&Ac[(wm * 64 + i * 16 + l16) * BK + quad * 8];
      bfr[i] = *(const bf16x8*)&Bc[(wn * 64 + i * 16 + l16) * BK + quad * 8];
    }
#pragma unroll
    for (int i = 0; i < 4; ++i)
#pragma unroll
      for (int j = 0; j < 4; ++j)
        acc[i][j] = MFMA16(af[i], bfr[j], acc[i][j]);
    asm volatile("s_waitcnt lgkmcnt(0)" ::: "memory");
    __builtin_amdgcn_s_barrier();
  }
#pragma unroll
  for (int i = 0; i < 4; ++i) {
#pragma unroll
    for (int j = 0; j < 4; ++j) {
#pragma unroll
      for (int rr = 0; rr < 4; ++rr) {
        int row = m0 + wm * 64 + i * 16 + quad * 4 + rr;
        int col = n0 + wn * 64 + j * 16 + l16;
        float v = acc[i][j][rr];
        if (mode == 3) {
          ((float*)out)[(size_t)row * DIM + col] = v + bias[col];
        } else if (mode == 2) {
          int b = row / T2;
          int t = row - b * T2;
          ((bf16*)out)[((size_t)b * DIM + col) * T2P + t] = (bf16)v;
        } else {
          ((bf16*)out)[(size_t)row * DIM + col] = (bf16)(v * scale);
        }
      }
    }
  }
}

__global__ __launch_bounds__(256)
void qkv_gemm_kernel(const bf16* q_act, const bf16* k_act, const bf16* v_act,
                     const bf16* wqb, const bf16* wkb, const bf16* wvb,
                     bf16* Qp, bf16* Kp, bf16* Vtp, float qscale) {
  __shared__ bf16 Al[2 * BUFSZ];
  __shared__ bf16 Bl[2 * BUFSZ];
  int bx = blockIdx.x;
  int xp = bx & 7, j = bx >> 3;
  int t = (j / 3) * 24 + xp * 3 + (j % 3);
  if (t >= 882) return;
  const bf16 *A, *Bw; void* out; int mode, ti; float scale;
  if (t < 588)      { A = q_act; Bw = wqb; out = Qp;  mode = 1; scale = qscale; ti = t; }
  else if (t < 735) { A = k_act; Bw = wkb; out = Kp;  mode = 0; scale = 1.f; ti = t - 588; }
  else              { A = v_act; Bw = wvb; out = Vtp; mode = 2; scale = 1.f; ti = t - 735; }
  gemm_body(A, Bw, out, nullptr, mode, scale, (ti / 3) * 128, (ti % 3) * 128, Al, Bl);
}

__global__ __launch_bounds__(256)
void last_gemm_kernel(const bf16* A, const bf16* Bw, float* out, const float* bias) {
  __shared__ bf16 Al[2 * BUFSZ];
  __shared__ bf16 Bl[2 * BUFSZ];
  int bx = blockIdx.x;
  int xp = bx & 7, j = bx >> 3;
  int t = (j / 3) * 24 + xp * 3 + (j % 3);
  if (t >= 588) return;
  gemm_body(A, Bw, out, bias, 3, 1.f, (t / 3) * 128, (t % 3) * 128, Al, Bl);
}

// ---------------- flash attention, S^T/O^T form, 32x32 MFMA, in-register P --------
// R9 (proven): swapped QK^T lands P in the PV B-operand lane; exp2 in-reg ->
// bf16x2 pack -> __shfl_xor(32) -> PV. No P LDS. 16 KB LDS, launch_bounds(256,4).
__global__ __launch_bounds__(256, 4)
void attn_kernel(const bf16* __restrict__ Qp, const bf16* __restrict__ Kp,
                 const bf16* __restrict__ Vt, bf16* __restrict__ Ob) {
  __shared__ bf16 Kl[64 * 64];            // [t][d], chunk-XOR swizzled (8 KB)
  __shared__ bf16 Vl[64 * 64];            // [d][t], chunk-XOR swizzled (8 KB)
  int bx = blockIdx.x;
  int xcd = bx & 7, j = bx >> 3;
  int g = xcd + 8 * (j / 25);             // (b,h) group 0..47, fixed per XCD
  int qblk = j % 25;
  int h = g % 6;
  int b = g / 6;
  int tid = threadIdx.x, w = tid >> 6, lane = tid & 63;
  int l32 = lane & 31, hi = lane >> 5;
  int q0w = qblk * 128 + w * 32;

  // Q fragments, B-operand of 32x32x16: n=lane&31=q, k=hi*8+j -> d=kk*16+hi*8+j
  bf16x8 qf[4];
  {
    int qi = q0w + l32;
    qi = qi < T1 ? qi : T1 - 1;
    const bf16* qp = &Qp[((size_t)b * T1 + qi) * DIM + h * 64];
#pragma unroll
    for (int kk = 0; kk < 4; ++kk) qf[kk] = *(const bf16x8*)&qp[kk * 16 + hi * 8];
  }
  floatx16 oacc[2];
  oacc[0] = (floatx16)0.f;
  oacc[1] = (floatx16)0.f;
  float lsum = 0.f;

  int rsub = lane >> 3;
  int chnk = (lane & 7) ^ rsub;
  const bf16* kg0 = &Kp[((size_t)b * T2 + w * 16 + rsub) * DIM + h * 64 + chnk * 8];
  const bf16* kg1 = kg0 + (size_t)8 * DIM;
  const bf16* vg0 = &Vt[((size_t)b * DIM + h * 64 + w * 16 + rsub) * T2P + chnk * 8];
  const bf16* vg1 = vg0 + (size_t)8 * T2P;
  bf16* kl0 = &Kl[(w * 16) * 64];
  bf16* kl1 = &Kl[(w * 16 + 8) * 64];
  bf16* vl0 = &Vl[(w * 16) * 64];
  bf16* vl1 = &Vl[(w * 16 + 8) * 64];

  int key = lane & 7;                     // fragment-read swizzle key (= row&7)

  for (int it = 0; it < 12; ++it) {
    __syncthreads();                      // prev iter's tile reads done
    gload_lds16(kg0, kl0);
    gload_lds16(kg1, kl1);
    gload_lds16(vg0, vl0);
    gload_lds16(vg1, vl1);
    __syncthreads();                      // drains vmcnt: tiles ready
#pragma unroll
    for (int tt = 0; tt < 2; ++tt) {      // two 32-t tiles
      floatx16 s = (floatx16)0.f;
#pragma unroll
      for (int kk = 0; kk < 4; ++kk) {    // d = kk*16 + hi*8 + j
        bf16x8 kf = *(const bf16x8*)&Kl[(tt * 32 + l32) * 64 + ((kk * 2 + hi) ^ key) * 8];
        s = MFMA32(kf, qf[kk], s);
      }
      float e[16];
#pragma unroll
      for (int r = 0; r < 16; ++r) {
        e[r] = __builtin_amdgcn_exp2f(s[r]);
        lsum += e[r];
      }
#pragma unroll
      for (int kkl = 0; kkl < 2; ++kkl) {
        int r0 = kkl * 8;
        u32 pA = pk2(e[r0 + 0], e[r0 + 1]);
        u32 pB = pk2(e[r0 + 2], e[r0 + 3]);
        u32 pC = pk2(e[r0 + 4], e[r0 + 5]);
        u32 pD = pk2(e[r0 + 6], e[r0 + 7]);
        u32 sA = __shfl_xor(pA, 32);
        u32 sB = __shfl_xor(pB, 32);
        u32 sC = __shfl_xor(pC, 32);
        u32 sD = __shfl_xor(pD, 32);
        union { u32 u[4]; bf16x8 v; } pf;
        pf.u[0] = hi ? sC : pA;
        pf.u[1] = hi ? sD : pB;
        pf.u[2] = hi ? pC : sA;
        pf.u[3] = hi ? pD : sB;
        int kk = tt * 2 + kkl;            // t-chunk for V: t = kk*16 + hi*8 + j
#pragma unroll
        for (int dt = 0; dt < 2; ++dt) {
          bf16x8 vf = *(const bf16x8*)&Vl[(dt * 32 + l32) * 64 + ((kk * 2 + hi) ^ key) * 8];
          oacc[dt] = MFMA32(vf, pf.v, oacc[dt]);
        }
      }
    }
    kg0 += (size_t)64 * DIM; kg1 += (size_t)64 * DIM;
    vg0 += 64; vg1 += 64;
  }
  // tail: t 768..783 (16 rows land in reg group r0..7; clamped rows never consumed)
  {
    int tq = 768 + l32;
    tq = tq < T2 ? tq : T2 - 1;
    const bf16* kp2 = &Kp[((size_t)b * T2 + tq) * DIM + h * 64];
    floatx16 s = (floatx16)0.f;
#pragma unroll
    for (int kk = 0; kk < 4; ++kk) {
      bf16x8 kf = *(const bf16x8*)&kp2[kk * 16 + hi * 8];
      s = MFMA32(kf, qf[kk], s);
    }
    float e[8];
#pragma unroll
    for (int r = 0; r < 8; ++r) {
      e[r] = __builtin_amdgcn_exp2f(s[r]);
      lsum += e[r];
    }
    u32 pA = pk2(e[0], e[1]);
    u32 pB = pk2(e[2], e[3]);
    u32 pC = pk2(e[4], e[5]);
    u32 pD = pk2(e[6], e[7]);
    u32 sA = __shfl_xor(pA, 32);
    u32 sB = __shfl_xor(pB, 32);
    u32 sC = __shfl_xor(pC, 32);
    u32 sD = __shfl_xor(pD, 32);
    union { u32 u[4]; bf16x8 v; } pf;
    pf.u[0] = hi ? sC : pA;
    pf.u[1] = hi ? sD : pB;
    pf.u[2] = hi ? pC : sA;
    pf.u[3] = hi ? pD : sB;
#pragma unroll
    for (int dt = 0; dt < 2; ++dt) {
      const bf16* vp2 = &Vt[((size_t)b * DIM + h * 64 + dt * 32 + l32) * T2P + 768 + hi * 8];
      bf16x8 vf = *(const bf16x8*)vp2;
      oacc[dt] = MFMA32(vf, pf.v, oacc[dt]);
    }
  }
  // epilogue
  lsum += __shfl_xor(lsum, 32);
  float inv = 1.f / lsum;
  int qg = q0w + l32;
  if (qg < T1) {
    bf16* op = &Ob[((size_t)b * T1 + qg) * DIM + h * 64];
#pragma unroll
    for (int dt = 0; dt < 2; ++dt) {
#pragma unroll
      for (int gr = 0; gr < 4; ++gr) {
        bf16x4 ov = (bf16x4){(bf16)(oacc[dt][gr * 4 + 0] * inv),
                             (bf16)(oacc[dt][gr * 4 + 1] * inv),
                             (bf16)(oacc[dt][gr * 4 + 2] * inv),
                             (bf16)(oacc[dt][gr * 4 + 3] * inv)};
        *(bf16x4*)&op[dt * 32 + gr * 8 + hi * 4] = ov;
      }
    }
  }
}

// ---------------- launch ----------------
extern "C" void kernel_launch(void* const* d_in, const int* in_sizes, int n_in,
                              void* d_out, int out_size, void* d_ws, size_t ws_size,
                              hipStream_t stream) {
  (void)in_sizes; (void)n_in; (void)out_size; (void)ws_size;
  const float* x      = (const float*)d_in[0];
  const float* conv_q = (const float*)d_in[3];
  const float* bnq_s  = (const float*)d_in[4];
  const float* bnq_b  = (const float*)d_in[5];
  const float* bnq_m  = (const float*)d_in[6];
  const float* bnq_v  = (const float*)d_in[7];
  const float* conv_k = (const float*)d_in[8];
  const float* bnk_s  = (const float*)d_in[9];
  const float* bnk_b  = (const float*)d_in[10];
  const float* bnk_m  = (const float*)d_in[11];
  const float* bnk_v  = (const float*)d_in[12];
  const float* conv_v = (const float*)d_in[13];
  const float* bnv_s  = (const float*)d_in[14];
  const float* bnv_b  = (const float*)d_in[15];
  const float* bnv_m  = (const float*)d_in[16];
  const float* bnv_v  = (const float*)d_in[17];
  const float* wq     = (const float*)d_in[18];
  const float* wk     = (const float*)d_in[19];
  const float* wv     = (const float*)d_in[20];
  const float* wl     = (const float*)d_in[21];
  const float* b_last = (const float*)d_in[22];

  char* ws = (char*)d_ws;
  bf16* q_act = (bf16*)(ws + 0);               // 19267584; reused as attention output
  bf16* k_act = (bf16*)(ws + 19267584);        // 4816896
  bf16* v_act = (bf16*)(ws + 24084480);        // 4816896
  bf16* Qp    = (bf16*)(ws + 28901376);        // 19267584 (pre-scaled by SCALE*log2e)
  bf16* Kp    = (bf16*)(ws + 48168960);        // 4816896
  bf16* Vtp   = (bf16*)(ws + 52985856);        // 8*384*832*2 = 5111808  [B][384][T2P]
  bf16* wqb   = (bf16*)(ws + 58097664);        // 294912 each, x4
  bf16* wkb   = wqb + 147456;
  bf16* wvb   = wkb + 147456;
  bf16* wlb   = wvb + 147456;

  const float QSCALE = 0.05103103630798288f * 1.4426950408889634f;  // 384^-0.5 * log2e

  conv_fused_kernel<<<B_ * 14 * 14, DIM, 0, stream>>>(
      x,
      conv_q, bnq_s, bnq_b, bnq_m, bnq_v,
      conv_k, bnk_s, bnk_b, bnk_m, bnk_v,
      conv_v, bnv_s, bnv_b, bnv_m, bnv_v,
      q_act, k_act, v_act,
      wq, wk, wv, wl, wqb, wkb, wvb, wlb);

  qkv_gemm_kernel<<<888, 256, 0, stream>>>(q_act, k_act, v_act, wqb, wkb, wvb,
                                           Qp, Kp, Vtp, QSCALE);

  attn_kernel<<<25 * 6 * B_, 256, 0, stream>>>(Qp, Kp, Vtp, q_act);

  last_gemm_kernel<<<600, 256, 0, stream>>>(q_act, wlb, (float*)d_out, b_last);
}

// Round 10
// 231.523 us; speedup vs baseline: 1.3128x; 1.0175x over previous
//
#include <hip/hip_runtime.h>
#include <hip/hip_bf16.h>

typedef __bf16 bf16;
typedef __attribute__((ext_vector_type(8))) __bf16 bf16x8;
typedef __attribute__((ext_vector_type(4))) __bf16 bf16x4;
typedef __attribute__((ext_vector_type(2))) __bf16 bf16x2;
typedef __attribute__((ext_vector_type(4))) float floatx4;
typedef __attribute__((ext_vector_type(16))) float floatx16;
typedef unsigned int u32;

#define MFMA16(a, b, c) __builtin_amdgcn_mfma_f32_16x16x32_bf16((a), (b), (c), 0, 0, 0)
#define MFMA32(a, b, c) __builtin_amdgcn_mfma_f32_32x32x16_bf16((a), (b), (c), 0, 0, 0)

#define DIM 384
#define T1 3136   // 56*56
#define T2 784    // 28*28
#define T2P 832   // padded t for Vt columns
#define B_ 8
#define EPSV 1e-5f

__device__ __forceinline__ void gload_lds16(const bf16* g, bf16* l) {
  __builtin_amdgcn_global_load_lds(
      (const __attribute__((address_space(1))) void*)g,
      (__attribute__((address_space(3))) void*)l, 16, 0, 0);
}

__device__ __forceinline__ u32 pk2(float a, float b) {
  bf16x2 t = (bf16x2){(bf16)a, (bf16)b};
  return *reinterpret_cast<u32*>(&t);
}

// ---------------- fused depthwise convs + BN + wcvt, 4x4 spatial tile --------------
// R14 (proven: -12 us): 4x4 output tile, halo in[6][6], kv 2x2 in every block.
__global__ void conv_fused_kernel(const float* __restrict__ x,
    const float* __restrict__ wqc, const float* __restrict__ gq, const float* __restrict__ bq,
    const float* __restrict__ mq, const float* __restrict__ vq,
    const float* __restrict__ wkc, const float* __restrict__ gk, const float* __restrict__ bk,
    const float* __restrict__ mk, const float* __restrict__ vk,
    const float* __restrict__ wvc, const float* __restrict__ gv, const float* __restrict__ bv,
    const float* __restrict__ mv, const float* __restrict__ vvv,
    bf16* __restrict__ qout, bf16* __restrict__ kout, bf16* __restrict__ vout,
    const float* __restrict__ w0, const float* __restrict__ w1,
    const float* __restrict__ w2, const float* __restrict__ w3,
    bf16* __restrict__ d0, bf16* __restrict__ d1,
    bf16* __restrict__ d2, bf16* __restrict__ d3) {
  int blk = blockIdx.x;
  int c = threadIdx.x;           // 0..383
  int gid = blk * DIM + c;
  if (gid < 147456) {            // folded weight conversion (first 384 blocks)
    d0[gid] = (bf16)w0[gid]; d1[gid] = (bf16)w1[gid];
    d2[gid] = (bf16)w2[gid]; d3[gid] = (bf16)w3[gid];
  }
  int xg = blk % 14;
  int yg = (blk / 14) % 14;
  int b = blk / 196;
  int x0 = xg * 4, y0 = yg * 4;
  const float* xb = x + (size_t)b * T1 * DIM;
  float in[6][6];
#pragma unroll
  for (int r = 0; r < 6; ++r) {
    int yy = y0 + r - 1;
#pragma unroll
    for (int cc = 0; cc < 6; ++cc) {
      int xc = x0 + cc - 1;
      in[r][cc] = (yy >= 0 && yy < 56 && xc >= 0 && xc < 56)
                      ? xb[(yy * 56 + xc) * DIM + c] : 0.f;
    }
  }
  // q path: 4x4 outputs
  {
    float wr[9];
#pragma unroll
    for (int i = 0; i < 9; ++i) wr[i] = wqc[c * 9 + i];
    float a = rsqrtf(vq[c] + EPSV) * gq[c];
    float bia = bq[c] - mq[c] * a;
#pragma unroll
    for (int py = 0; py < 4; ++py) {
#pragma unroll
      for (int px = 0; px < 4; ++px) {
        float s = 0.f;
#pragma unroll
        for (int r = 0; r < 3; ++r)
#pragma unroll
          for (int dx = 0; dx < 3; ++dx) s += in[py + r][px + dx] * wr[r * 3 + dx];
        qout[((size_t)b * T1 + (y0 + py) * 56 + x0 + px) * DIM + c] = (bf16)(s * a + bia);
      }
    }
  }
  // kv path: 2x2 stride-2 outputs (y0, x0 even)
  {
    float wk9[9], wv9[9];
#pragma unroll
    for (int i = 0; i < 9; ++i) { wk9[i] = wkc[c * 9 + i]; wv9[i] = wvc[c * 9 + i]; }
    float ak = rsqrtf(vk[c] + EPSV) * gk[c];
    float av = rsqrtf(vvv[c] + EPSV) * gv[c];
    float bik = bk[c] - mk[c] * ak;
    float biv = bv[c] - mv[c] * av;
#pragma unroll
    for (int py = 0; py < 2; ++py) {
#pragma unroll
      for (int px = 0; px < 2; ++px) {
        float sk = 0.f, sv = 0.f;
#pragma unroll
        for (int r = 0; r < 3; ++r)
#pragma unroll
          for (int dx = 0; dx < 3; ++dx) {
            float xv = in[2 * py + r][2 * px + dx];
            sk += xv * wk9[r * 3 + dx];
            sv += xv * wv9[r * 3 + dx];
          }
        size_t o = ((size_t)b * T2 + (y0 / 2 + py) * 28 + (x0 / 2 + px)) * DIM + c;
        kout[o] = (bf16)(sk * ak + bik);
        vout[o] = (bf16)(sv * av + biv);
      }
    }
  }
}

// ---------------- shared GEMM body: C[128,128] tile of A[M,384] @ W[384,384]^T ------
// R15: depth-2 staging pipeline. R7's double-buffer gave only ~1 step (~300-600 cy)
// of slack, but first-touch A-panel rows are compulsory HBM misses (~900 cy).
// Triple-buffered LDS (48 KB), stage K-slice s+2 at step s, steady-state
// s_waitcnt vmcnt(8): the wait targets loads issued TWO steps (~600-1200 cy) ago.
// Ledger: at step s, outstanding = stage(s)+stage(s+1)+stage(s+2) = 12 ->
// vmcnt(8) retires exactly stage(s); tail vmcnt(4) then vmcnt(0). Buffer (s+2)%3
// was read at step s-1 whose trailing lgkmcnt(0)+barrier retired all reads.
#define BK 32
#define BUFSZ (128 * BK)
__device__ __forceinline__
void gemm_body(const bf16* A, const bf16* Bw, void* out, const float* bias,
               int mode, float scale, int m0, int n0, bf16* Al, bf16* Bl) {
  int tid = threadIdx.x;
  int w = tid >> 6, lane = tid & 63;
  int wm = w >> 1, wn = w & 1;
  int l16 = lane & 15, quad = lane >> 4;
  floatx4 acc[4][4];
#pragma unroll
  for (int i = 0; i < 4; ++i)
#pragma unroll
    for (int j = 0; j < 4; ++j) acc[i][j] = (floatx4){0.f, 0.f, 0.f, 0.f};

  int srow = w * 32 + (lane >> 2);
  int scol = (lane & 3) * 8;
  const bf16* ag0 = &A[(size_t)(m0 + srow) * DIM + scol];
  const bf16* ag1 = ag0 + (size_t)16 * DIM;
  const bf16* bg0 = &Bw[(size_t)(n0 + srow) * DIM + scol];
  const bf16* bg1 = bg0 + (size_t)16 * DIM;
  int lofs0 = (w * 32) * BK;
  int lofs1 = (w * 32 + 16) * BK;

#define STAGE_Q(s) {                                   \
    bf16* an = Al + ((s) % 3) * BUFSZ;                 \
    bf16* bn = Bl + ((s) % 3) * BUFSZ;                 \
    const int kk = (s) * BK;                           \
    gload_lds16(ag0 + kk, an + lofs0);                 \
    gload_lds16(ag1 + kk, an + lofs1);                 \
    gload_lds16(bg0 + kk, bn + lofs0);                 \
    gload_lds16(bg1 + kk, bn + lofs1);                 \
  }

  STAGE_Q(0);
  STAGE_Q(1);

  const int NS = DIM / BK;  // 12
#pragma unroll
  for (int s = 0; s < NS; ++s) {
    if (s + 2 < NS) {
      STAGE_Q(s + 2);
      asm volatile("s_waitcnt vmcnt(8)" ::: "memory");  // retire stage(s)'s 4
    } else if (s + 1 < NS) {
      asm volatile("s_waitcnt vmcnt(4)" ::: "memory");
    } else {
      asm volatile("s_waitcnt vmcnt(0)" ::: "memory");
    }
    __builtin_amdgcn_s_barrier();          // current buffer globally visible
    const bf16* Ac = Al + (s % 3) * BUFSZ;
    const bf16* Bc = Bl + (s % 3) * BUFSZ;
    bf16x8 af[4], bfr[4];
#pragma unroll
    for (int i = 0; i < 4; ++i) {
      af[i]  = *(const bf16x8*)&Ac[(wm * 64 + i * 16 + l16) * BK + quad * 8];
      bfr[i] = *(const bf16x8*)&Bc[(wn * 64 + i * 16 + l16) * BK + quad * 8];
    }
#pragma unroll
    for (int i = 0; i < 4; ++i)
#pragma unroll
      for (int j = 0; j < 4; ++j)
        acc[i][j] = MFMA16(af[i], bfr[j], acc[i][j]);
    asm volatile("s_waitcnt lgkmcnt(0)" ::: "memory");  // our reads of this buf done
    __builtin_amdgcn_s_barrier();
  }
#undef STAGE_Q
#pragma unroll
  for (int i = 0; i < 4; ++i) {
#pragma unroll
    for (int j = 0; j < 4; ++j) {
#pragma unroll
      for (int rr = 0; rr < 4; ++rr) {
        int row = m0 + wm * 64 + i * 16 + quad * 4 + rr;
        int col = n0 + wn * 64 + j * 16 + l16;
        float v = acc[i][j][rr];
        if (mode == 3) {
          ((float*)out)[(size_t)row * DIM + col] = v + bias[col];
        } else if (mode == 2) {
          int b = row / T2;
          int t = row - b * T2;
          ((bf16*)out)[((size_t)b * DIM + col) * T2P + t] = (bf16)v;
        } else {
          ((bf16*)out)[(size_t)row * DIM + col] = (bf16)(v * scale);
        }
      }
    }
  }
}

__global__ __launch_bounds__(256)
void qkv_gemm_kernel(const bf16* q_act, const bf16* k_act, const bf16* v_act,
                     const bf16* wqb, const bf16* wkb, const bf16* wvb,
                     bf16* Qp, bf16* Kp, bf16* Vtp, float qscale) {
  __shared__ bf16 Al[3 * BUFSZ];   // 24 KB
  __shared__ bf16 Bl[3 * BUFSZ];   // 24 KB
  int bx = blockIdx.x;
  int xp = bx & 7, j = bx >> 3;
  int t = (j / 3) * 24 + xp * 3 + (j % 3);
  if (t >= 882) return;
  const bf16 *A, *Bw; void* out; int mode, ti; float scale;
  if (t < 588)      { A = q_act; Bw = wqb; out = Qp;  mode = 1; scale = qscale; ti = t; }
  else if (t < 735) { A = k_act; Bw = wkb; out = Kp;  mode = 0; scale = 1.f; ti = t - 588; }
  else              { A = v_act; Bw = wvb; out = Vtp; mode = 2; scale = 1.f; ti = t - 735; }
  gemm_body(A, Bw, out, nullptr, mode, scale, (ti / 3) * 128, (ti % 3) * 128, Al, Bl);
}

__global__ __launch_bounds__(256)
void last_gemm_kernel(const bf16* A, const bf16* Bw, float* out, const float* bias) {
  __shared__ bf16 Al[3 * BUFSZ];
  __shared__ bf16 Bl[3 * BUFSZ];
  int bx = blockIdx.x;
  int xp = bx & 7, j = bx >> 3;
  int t = (j / 3) * 24 + xp * 3 + (j % 3);
  if (t >= 588) return;
  gemm_body(A, Bw, out, bias, 3, 1.f, (t / 3) * 128, (t % 3) * 128, Al, Bl);
}

// ---------------- flash attention, S^T/O^T form, 32x32 MFMA, in-register P --------
// R9 (proven): swapped QK^T lands P in the PV B-operand lane; exp2 in-reg ->
// bf16x2 pack -> __shfl_xor(32) -> PV. No P LDS. 16 KB LDS, launch_bounds(256,4).
__global__ __launch_bounds__(256, 4)
void attn_kernel(const bf16* __restrict__ Qp, const bf16* __restrict__ Kp,
                 const bf16* __restrict__ Vt, bf16* __restrict__ Ob) {
  __shared__ bf16 Kl[64 * 64];            // [t][d], chunk-XOR swizzled (8 KB)
  __shared__ bf16 Vl[64 * 64];            // [d][t], chunk-XOR swizzled (8 KB)
  int bx = blockIdx.x;
  int xcd = bx & 7, j = bx >> 3;
  int g = xcd + 8 * (j / 25);             // (b,h) group 0..47, fixed per XCD
  int qblk = j % 25;
  int h = g % 6;
  int b = g / 6;
  int tid = threadIdx.x, w = tid >> 6, lane = tid & 63;
  int l32 = lane & 31, hi = lane >> 5;
  int q0w = qblk * 128 + w * 32;

  // Q fragments, B-operand of 32x32x16: n=lane&31=q, k=hi*8+j -> d=kk*16+hi*8+j
  bf16x8 qf[4];
  {
    int qi = q0w + l32;
    qi = qi < T1 ? qi : T1 - 1;
    const bf16* qp = &Qp[((size_t)b * T1 + qi) * DIM + h * 64];
#pragma unroll
    for (int kk = 0; kk < 4; ++kk) qf[kk] = *(const bf16x8*)&qp[kk * 16 + hi * 8];
  }
  floatx16 oacc[2];
  oacc[0] = (floatx16)0.f;
  oacc[1] = (floatx16)0.f;
  float lsum = 0.f;

  int rsub = lane >> 3;
  int chnk = (lane & 7) ^ rsub;
  const bf16* kg0 = &Kp[((size_t)b * T2 + w * 16 + rsub) * DIM + h * 64 + chnk * 8];
  const bf16* kg1 = kg0 + (size_t)8 * DIM;
  const bf16* vg0 = &Vt[((size_t)b * DIM + h * 64 + w * 16 + rsub) * T2P + chnk * 8];
  const bf16* vg1 = vg0 + (size_t)8 * T2P;
  bf16* kl0 = &Kl[(w * 16) * 64];
  bf16* kl1 = &Kl[(w * 16 + 8) * 64];
  bf16* vl0 = &Vl[(w * 16) * 64];
  bf16* vl1 = &Vl[(w * 16 + 8) * 64];

  int key = lane & 7;                     // fragment-read swizzle key (= row&7)

  for (int it = 0; it < 12; ++it) {
    __syncthreads();                      // prev iter's tile reads done
    gload_lds16(kg0, kl0);
    gload_lds16(kg1, kl1);
    gload_lds16(vg0, vl0);
    gload_lds16(vg1, vl1);
    __syncthreads();                      // drains vmcnt: tiles ready
#pragma unroll
    for (int tt = 0; tt < 2; ++tt) {      // two 32-t tiles
      floatx16 s = (floatx16)0.f;
#pragma unroll
      for (int kk = 0; kk < 4; ++kk) {    // d = kk*16 + hi*8 + j
        bf16x8 kf = *(const bf16x8*)&Kl[(tt * 32 + l32) * 64 + ((kk * 2 + hi) ^ key) * 8];
        s = MFMA32(kf, qf[kk], s);
      }
      float e[16];
#pragma unroll
      for (int r = 0; r < 16; ++r) {
        e[r] = __builtin_amdgcn_exp2f(s[r]);
        lsum += e[r];
      }
#pragma unroll
      for (int kkl = 0; kkl < 2; ++kkl) {
        int r0 = kkl * 8;
        u32 pA = pk2(e[r0 + 0], e[r0 + 1]);
        u32 pB = pk2(e[r0 + 2], e[r0 + 3]);
        u32 pC = pk2(e[r0 + 4], e[r0 + 5]);
        u32 pD = pk2(e[r0 + 6], e[r0 + 7]);
        u32 sA = __shfl_xor(pA, 32);
        u32 sB = __shfl_xor(pB, 32);
        u32 sC = __shfl_xor(pC, 32);
        u32 sD = __shfl_xor(pD, 32);
        union { u32 u[4]; bf16x8 v; } pf;
        pf.u[0] = hi ? sC : pA;
        pf.u[1] = hi ? sD : pB;
        pf.u[2] = hi ? pC : sA;
        pf.u[3] = hi ? pD : sB;
        int kk = tt * 2 + kkl;            // t-chunk for V: t = kk*16 + hi*8 + j
#pragma unroll
        for (int dt = 0; dt < 2; ++dt) {
          bf16x8 vf = *(const bf16x8*)&Vl[(dt * 32 + l32) * 64 + ((kk * 2 + hi) ^ key) * 8];
          oacc[dt] = MFMA32(vf, pf.v, oacc[dt]);
        }
      }
    }
    kg0 += (size_t)64 * DIM; kg1 += (size_t)64 * DIM;
    vg0 += 64; vg1 += 64;
  }
  // tail: t 768..783 (16 rows land in reg group r0..7; clamped rows never consumed)
  {
    int tq = 768 + l32;
    tq = tq < T2 ? tq : T2 - 1;
    const bf16* kp2 = &Kp[((size_t)b * T2 + tq) * DIM + h * 64];
    floatx16 s = (floatx16)0.f;
#pragma unroll
    for (int kk = 0; kk < 4; ++kk) {
      bf16x8 kf = *(const bf16x8*)&kp2[kk * 16 + hi * 8];
      s = MFMA32(kf, qf[kk], s);
    }
    float e[8];
#pragma unroll
    for (int r = 0; r < 8; ++r) {
      e[r] = __builtin_amdgcn_exp2f(s[r]);
      lsum += e[r];
    }
    u32 pA = pk2(e[0], e[1]);
    u32 pB = pk2(e[2], e[3]);
    u32 pC = pk2(e[4], e[5]);
    u32 pD = pk2(e[6], e[7]);
    u32 sA = __shfl_xor(pA, 32);
    u32 sB = __shfl_xor(pB, 32);
    u32 sC = __shfl_xor(pC, 32);
    u32 sD = __shfl_xor(pD, 32);
    union { u32 u[4]; bf16x8 v; } pf;
    pf.u[0] = hi ? sC : pA;
    pf.u[1] = hi ? sD : pB;
    pf.u[2] = hi ? pC : sA;
    pf.u[3] = hi ? pD : sB;
#pragma unroll
    for (int dt = 0; dt < 2; ++dt) {
      const bf16* vp2 = &Vt[((size_t)b * DIM + h * 64 + dt * 32 + l32) * T2P + 768 + hi * 8];
      bf16x8 vf = *(const bf16x8*)vp2;
      oacc[dt] = MFMA32(vf, pf.v, oacc[dt]);
    }
  }
  // epilogue
  lsum += __shfl_xor(lsum, 32);
  float inv = 1.f / lsum;
  int qg = q0w + l32;
  if (qg < T1) {
    bf16* op = &Ob[((size_t)b * T1 + qg) * DIM + h * 64];
#pragma unroll
    for (int dt = 0; dt < 2; ++dt) {
#pragma unroll
      for (int gr = 0; gr < 4; ++gr) {
        bf16x4 ov = (bf16x4){(bf16)(oacc[dt][gr * 4 + 0] * inv),
                             (bf16)(oacc[dt][gr * 4 + 1] * inv),
                             (bf16)(oacc[dt][gr * 4 + 2] * inv),
                             (bf16)(oacc[dt][gr * 4 + 3] * inv)};
        *(bf16x4*)&op[dt * 32 + gr * 8 + hi * 4] = ov;
      }
    }
  }
}

// ---------------- launch ----------------
extern "C" void kernel_launch(void* const* d_in, const int* in_sizes, int n_in,
                              void* d_out, int out_size, void* d_ws, size_t ws_size,
                              hipStream_t stream) {
  (void)in_sizes; (void)n_in; (void)out_size; (void)ws_size;
  const float* x      = (const float*)d_in[0];
  const float* conv_q = (const float*)d_in[3];
  const float* bnq_s  = (const float*)d_in[4];
  const float* bnq_b  = (const float*)d_in[5];
  const float* bnq_m  = (const float*)d_in[6];
  const float* bnq_v  = (const float*)d_in[7];
  const float* conv_k = (const float*)d_in[8];
  const float* bnk_s  = (const float*)d_in[9];
  const float* bnk_b  = (const float*)d_in[10];
  const float* bnk_m  = (const float*)d_in[11];
  const float* bnk_v  = (const float*)d_in[12];
  const float* conv_v = (const float*)d_in[13];
  const float* bnv_s  = (const float*)d_in[14];
  const float* bnv_b  = (const float*)d_in[15];
  const float* bnv_m  = (const float*)d_in[16];
  const float* bnv_v  = (const float*)d_in[17];
  const float* wq     = (const float*)d_in[18];
  const float* wk     = (const float*)d_in[19];
  const float* wv     = (const float*)d_in[20];
  const float* wl     = (const float*)d_in[21];
  const float* b_last = (const float*)d_in[22];

  char* ws = (char*)d_ws;
  bf16* q_act = (bf16*)(ws + 0);               // 19267584; reused as attention output
  bf16* k_act = (bf16*)(ws + 19267584);        // 4816896
  bf16* v_act = (bf16*)(ws + 24084480);        // 4816896
  bf16* Qp    = (bf16*)(ws + 28901376);        // 19267584 (pre-scaled by SCALE*log2e)
  bf16* Kp    = (bf16*)(ws + 48168960);        // 4816896
  bf16* Vtp   = (bf16*)(ws + 52985856);        // 8*384*832*2 = 5111808  [B][384][T2P]
  bf16* wqb   = (bf16*)(ws + 58097664);        // 294912 each, x4
  bf16* wkb   = wqb + 147456;
  bf16* wvb   = wkb + 147456;
  bf16* wlb   = wvb + 147456;

  const float QSCALE = 0.05103103630798288f * 1.4426950408889634f;  // 384^-0.5 * log2e

  conv_fused_kernel<<<B_ * 14 * 14, DIM, 0, stream>>>(
      x,
      conv_q, bnq_s, bnq_b, bnq_m, bnq_v,
      conv_k, bnk_s, bnk_b, bnk_m, bnk_v,
      conv_v, bnv_s, bnv_b, bnv_m, bnv_v,
      q_act, k_act, v_act,
      wq, wk, wv, wl, wqb, wkb, wvb, wlb);

  qkv_gemm_kernel<<<888, 256, 0, stream>>>(q_act, k_act, v_act, wqb, wkb, wvb,
                                           Qp, Kp, Vtp, QSCALE);

  attn_kernel<<<25 * 6 * B_, 256, 0, stream>>>(Qp, Kp, Vtp, q_act);

  last_gemm_kernel<<<600, 256, 0, stream>>>(q_act, wlb, (float*)d_out, b_last);
}